// Round 10
// baseline (685.836 us; speedup 1.0000x reference)
//
#include <hip/hip_runtime.h>
#include <hip/hip_bf16.h>
#include <math.h>

#define HC 512
#define NHEAD 4
#define NEG_SLOPE 0.2f
#define EPS_BN 1e-5f

typedef __attribute__((ext_vector_type(8))) _Float16 half8;
typedef __attribute__((ext_vector_type(4))) _Float16 half4v;
typedef __attribute__((ext_vector_type(4))) float f32x4;

#define GLOAD16(gptr, lptr)                                                      \
    __builtin_amdgcn_global_load_lds(                                            \
        (const __attribute__((address_space(1))) unsigned int*)(gptr),           \
        (__attribute__((address_space(3))) unsigned int*)(lptr), 16, 0, 0)

// ---------------------------------------------------------------------------
// CSR build with per-node padding to a multiple of 8.  rowptr = padded start,
// deg = real degree.  Pad slots: csrc=0 (memset), alpha=0 (memset once) so
// padded gather iterations contribute exactly 0.  Self-loops j in [E,E+N).
// ---------------------------------------------------------------------------
__global__ void hist_kernel(const int* __restrict__ dstE, int* __restrict__ cnt,
                            int E, int N) {
    int i = blockIdx.x * 256 + threadIdx.x;
    if (i < E + N) {
        int d = (i < E) ? dstE[i] : (i - E);
        atomicAdd(&cnt[d], 1);
    }
}

__global__ __launch_bounds__(1024) void scan_kernel(int* __restrict__ rowptr,
                                                    int* __restrict__ wr,
                                                    int* __restrict__ deg, int n) {
    __shared__ int wsum[16];
    __shared__ int carry_s;
    int t = threadIdx.x, lane = t & 63, wv = t >> 6;
    if (t == 0) carry_s = 0;
    __syncthreads();
    for (int base = 0; base < n; base += 1024) {
        int c = (base + t < n) ? rowptr[base + t] : 0;
        int v = (c + 7) & ~7;               // padded degree
        int x = v;
#pragma unroll
        for (int off = 1; off < 64; off <<= 1) {
            int y = __shfl_up(x, off);
            if (lane >= off) x += y;
        }
        if (lane == 63) wsum[wv] = x;
        __syncthreads();
        if (wv == 0) {
            int s = (lane < 16) ? wsum[lane] : 0;
#pragma unroll
            for (int off = 1; off < 16; off <<= 1) {
                int y = __shfl_up(s, off);
                if (lane >= off) s += y;
            }
            if (lane < 16) wsum[lane] = s;
        }
        __syncthreads();
        int woff = (wv == 0) ? 0 : wsum[wv - 1];
        int tot = wsum[15];
        int carry = carry_s;
        if (base + t < n) {
            int excl = carry + woff + x - v;
            rowptr[base + t] = excl;
            wr[base + t] = excl;
            deg[base + t] = c;
        }
        __syncthreads();
        if (t == 1023) carry_s = carry + tot;
        __syncthreads();
    }
    if (threadIdx.x == 0) rowptr[n] = carry_s;
}

__global__ void scatter_kernel(const int* __restrict__ srcE,
                               const int* __restrict__ dstE,
                               int* __restrict__ wr, int* __restrict__ csrc,
                               int E, int N) {
    int i = blockIdx.x * 256 + threadIdx.x;
    if (i < E + N) {
        int d = (i < E) ? dstE[i] : (i - E);
        int s = (i < E) ? srcE[i] : (i - E);
        int p = atomicAdd(&wr[d], 1);
        csrc[p] = s;
    }
}

// ---------------------------------------------------------------------------
// BN fold scalars: a_k = g*rsqrt(var+eps), d_k = bt - mu*a  (from double stats)
// ---------------------------------------------------------------------------
__global__ __launch_bounds__(256) void advec_kernel(const double* __restrict__ stats,
                                                    const float* __restrict__ g,
                                                    const float* __restrict__ bt,
                                                    float* __restrict__ avec,
                                                    float* __restrict__ dvec,
                                                    double invN) {
    int k = blockIdx.x * 256 + threadIdx.x;
    if (k >= HC) return;
    double mu = stats[k] * invN;
    double var = stats[HC + k] * invN - mu * mu;
    float a = g[k] * (float)rsqrt(var + (double)EPS_BN);
    avec[k] = a;
    dvec[k] = bt[k] - (float)mu * a;
}

// ---------------------------------------------------------------------------
// Weight transpose + optional per-row scale avec -> fp16 (single precision
// level; B-lo product dropped per round-10 error analysis).
// ---------------------------------------------------------------------------
__global__ __launch_bounds__(256) void wsplit_kernel(const float* __restrict__ W,
                                                     const float* __restrict__ avec,
                                                     _Float16* __restrict__ hiT,
                                                     int K, int Nc) {
    __shared__ float tile[32][33];
    int bx = blockIdx.x * 32;   // n
    int by = blockIdx.y * 32;   // k
    int tx = threadIdx.x & 31, ty = threadIdx.x >> 5;   // 32 x 8
#pragma unroll
    for (int r = 0; r < 32; r += 8)
        tile[ty + r][tx] = W[(size_t)(by + ty + r) * Nc + bx + tx];
    __syncthreads();
    int k = by + tx;
    float a = avec ? avec[k] : 1.f;
#pragma unroll
    for (int r = 0; r < 32; r += 8) {
        int n = bx + ty + r;
        hiT[(size_t)n * K + k] = (_Float16)(tile[tx][ty + r] * a);
    }
}

// bvec[j] = extra[j] + sum_k dvec[k] * W[k][j]   (one wave per j)
__global__ __launch_bounds__(256) void bvec_kernel(const float* __restrict__ W,
                                                   const float* __restrict__ dvec,
                                                   const float* __restrict__ extra,
                                                   float* __restrict__ bvec,
                                                   int K, int Nc) {
    int wv = (blockIdx.x * 256 + threadIdx.x) >> 6;
    int lane = threadIdx.x & 63;
    if (wv >= Nc) return;
    float s = 0.f;
    for (int k = lane; k < K; k += 64)
        s = fmaf(dvec[k], W[(size_t)k * Nc + wv], s);
#pragma unroll
    for (int off = 32; off; off >>= 1) s += __shfl_xor(s, off);
    if (lane == 0) bvec[wv] = s + (extra ? extra[wv] : 0.f);
}

__global__ __launch_bounds__(256) void xcvt_kernel(const float* __restrict__ x,
                                                   _Float16* __restrict__ xh, int total) {
    for (int i = blockIdx.x * 256 + threadIdx.x; i < total; i += gridDim.x * 256)
        xh[i] = (_Float16)x[i];
}

// ---------------------------------------------------------------------------
// fp16 GEMM: C = A[M,K] @ B[K,Nc] + bvec  (B given transposed [Nc][K]).
// 128x128 tile, BK=32, 2x2 waves, 16x16x32 f16 MFMA, XCD-aware swizzle.
// EPI 0: store fp16 h.  EPI 1: ReLU, store fp32.
// ---------------------------------------------------------------------------
template <int EPI>
__global__ __launch_bounds__(256) void mfma_gemm(const _Float16* __restrict__ A,
                                                 const _Float16* __restrict__ BT,
                                                 const float* __restrict__ bvec,
                                                 _Float16* __restrict__ H16,
                                                 float* __restrict__ C,
                                                 int M, int K, int Nc) {
    __shared__ _Float16 sm[2 * 4096];           // 16 KiB: A | B
    _Float16* sA = sm;
    _Float16* sB = sm + 4096;

    const int nwg = gridDim.x * gridDim.y;
    const int orig = blockIdx.y * gridDim.x + blockIdx.x;
    const int q = nwg >> 3, r = nwg & 7;
    const int xcd = orig & 7, local = orig >> 3;
    const int wgid = (xcd < r ? xcd * (q + 1) : r * (q + 1) + (xcd - r) * q) + local;
    const int bxi = wgid % gridDim.x, byi = wgid / gridDim.x;

    const int tid = threadIdx.x;
    const int wid = tid >> 6, lane = tid & 63;
    const int wm = wid >> 1, wn = wid & 1;      // wave grid 2x2, each 64x64
    const int bm = byi * 128, bn = bxi * 128;

    const int rowl = lane >> 2;
    const int cole = (lane & 3) * 8;
    const int c0 = wid * 2;

    const int frow = lane & 15;
    const int fko = (lane >> 4) * 8;

    f32x4 acc[4][4] = {};

    for (int k0 = 0; k0 < K; k0 += 32) {
#pragma unroll
        for (int cc = 0; cc < 2; ++cc) {
            int c = c0 + cc;
            int ra = bm + c * 16 + rowl; if (ra >= M) ra = M - 1;
            int rb = bn + c * 16 + rowl;
            GLOAD16(A + (size_t)ra * K + k0 + cole, &sA[c * 512]);
            GLOAD16(BT + (size_t)rb * K + k0 + cole, &sB[c * 512]);
        }
        __syncthreads();

        half8 av[4], bv[4];
#pragma unroll
        for (int mi = 0; mi < 4; ++mi) {
            int rr = wm * 64 + mi * 16 + frow;
            av[mi] = *(const half8*)&sA[rr * 32 + fko];
        }
#pragma unroll
        for (int ni = 0; ni < 4; ++ni) {
            int rr = wn * 64 + ni * 16 + frow;
            bv[ni] = *(const half8*)&sB[rr * 32 + fko];
        }
#pragma unroll
        for (int mi = 0; mi < 4; ++mi)
#pragma unroll
            for (int ni = 0; ni < 4; ++ni)
                acc[mi][ni] = __builtin_amdgcn_mfma_f32_16x16x32_f16(av[mi], bv[ni], acc[mi][ni], 0, 0, 0);
        __syncthreads();
    }

    const int crow = (lane >> 4) * 4;
    const int ccol = lane & 15;
#pragma unroll
    for (int mi = 0; mi < 4; ++mi)
#pragma unroll
        for (int ni = 0; ni < 4; ++ni) {
            int gc = bn + wn * 64 + ni * 16 + ccol;
            float bvv = bvec[gc];
#pragma unroll
            for (int rr = 0; rr < 4; ++rr) {
                int gr = bm + wm * 64 + mi * 16 + crow + rr;
                if (gr >= M) continue;
                float v = acc[mi][ni][rr] + bvv;
                if (EPI == 0) {
                    H16[(size_t)gr * Nc + gc] = (_Float16)v;
                } else {
                    C[(size_t)gr * Nc + gc] = fmaxf(v, 0.f);
                }
            }
        }
}

// ---------------------------------------------------------------------------
// Tiled fp32 GEMM (small MLP layer 2).  EPI 1 = +bias, ReLU.
// ---------------------------------------------------------------------------
template <int BM, int BN, int BK, int TM, int TN, int EPI>
__global__ __launch_bounds__(256) void gemm_k(const float* __restrict__ A,
                                              const float* __restrict__ B,
                                              const float* __restrict__ bias,
                                              float* __restrict__ C,
                                              int M, int K, int N) {
    constexpr int PAD = 4;
    __shared__ float sA[BK][BM + PAD];
    __shared__ float sB[BK][BN];

    const int tid = threadIdx.x;
    const int bm = blockIdx.y * BM, bn = blockIdx.x * BN;
    constexpr int TX = BN / TN;
    const int tx = tid % TX, ty = tid / TX;

    float acc[TM][TN] = {};

    constexpr int AF4 = BK / 4;
    const int a4 = tid % AF4;
    const int ar0 = tid / AF4;
    constexpr int AROWS = 256 / AF4;
    constexpr int APASS = BM / AROWS;

    constexpr int BF4 = BN / 4;
    const int b4 = tid % BF4;
    const int br0 = tid / BF4;
    constexpr int BROWS = 256 / BF4;
    constexpr int BPASS = BK / BROWS;

    for (int kt = 0; kt < K; kt += BK) {
        __syncthreads();
#pragma unroll
        for (int p = 0; p < APASS; ++p) {
            int row = ar0 + p * AROWS;
            int gr = bm + row;
            if (gr >= M) gr = M - 1;
            float4 v = *(const float4*)&A[(size_t)gr * K + kt + a4 * 4];
            sA[a4 * 4 + 0][row] = v.x;
            sA[a4 * 4 + 1][row] = v.y;
            sA[a4 * 4 + 2][row] = v.z;
            sA[a4 * 4 + 3][row] = v.w;
        }
#pragma unroll
        for (int p = 0; p < BPASS; ++p) {
            int row = br0 + p * BROWS;
            float4 v = *(const float4*)&B[(size_t)(kt + row) * N + bn + b4 * 4];
            *(float4*)&sB[row][b4 * 4] = v;
        }
        __syncthreads();
#pragma unroll
        for (int k = 0; k < BK; ++k) {
            float ar[TM], br[TN];
#pragma unroll
            for (int i = 0; i < TM; i += 4)
                *(float4*)&ar[i] = *(const float4*)&sA[k][ty * TM + i];
#pragma unroll
            for (int j = 0; j < TN; j += 4)
                *(float4*)&br[j] = *(const float4*)&sB[k][tx * TN + j];
#pragma unroll
            for (int i = 0; i < TM; ++i)
#pragma unroll
                for (int j = 0; j < TN; ++j)
                    acc[i][j] = fmaf(ar[i], br[j], acc[i][j]);
        }
    }

#pragma unroll
    for (int i = 0; i < TM; ++i) {
        int r = bm + ty * TM + i;
        if (r >= M) continue;
#pragma unroll
        for (int j = 0; j < TN; j += 4) {
            int c = bn + tx * TN + j;
            float4 v;
            v.x = acc[i][j + 0]; v.y = acc[i][j + 1];
            v.z = acc[i][j + 2]; v.w = acc[i][j + 3];
            if (EPI == 1) {
                v.x = fmaxf(v.x + bias[c + 0], 0.f);
                v.y = fmaxf(v.y + bias[c + 1], 0.f);
                v.z = fmaxf(v.z + bias[c + 2], 0.f);
                v.w = fmaxf(v.w + bias[c + 3], 0.f);
            }
            *(float4*)&C[(size_t)r * N + c] = v;
        }
    }
}

// ---------------------------------------------------------------------------
// Attention coefficients from fp16 h.  One wave per node.
// ---------------------------------------------------------------------------
__global__ __launch_bounds__(256) void al_kernel(const _Float16* __restrict__ h16,
                                                 const float* __restrict__ asrc,
                                                 const float* __restrict__ adst,
                                                 float* __restrict__ al_s,
                                                 float* __restrict__ al_d, int N) {
    int wid = (blockIdx.x * 256 + threadIdx.x) >> 6;
    int lane = threadIdx.x & 63;
    if (wid >= N) return;
    half8 hv = *(const half8*)(h16 + (size_t)wid * HC + lane * 8);
    float ss = 0.f, sd = 0.f;
#pragma unroll
    for (int j = 0; j < 8; ++j) {
        float v = (float)hv[j];
        ss = fmaf(v, asrc[lane * 8 + j], ss);
        sd = fmaf(v, adst[lane * 8 + j], sd);
    }
#pragma unroll
    for (int off = 8; off; off >>= 1) {
        ss += __shfl_xor(ss, off);
        sd += __shfl_xor(sd, off);
    }
    if ((lane & 15) == 0) {
        al_s[wid * NHEAD + (lane >> 4)] = ss;
        al_d[wid * NHEAD + (lane >> 4)] = sd;
    }
}

// ---------------------------------------------------------------------------
// attw: one wave per dst node.  Fast path (deg<=64): single load pass into
// registers.  Fallback: 3-pass loop.  Writes alpha for REAL edges only (pad
// slots stay 0 from the once-per-launch memset).
// ---------------------------------------------------------------------------
__global__ __launch_bounds__(256) void attw_kernel(const float* __restrict__ al_s,
                                                   const float* __restrict__ al_d,
                                                   const int* __restrict__ rowptr,
                                                   const int* __restrict__ degv,
                                                   const int* __restrict__ csrc,
                                                   float4* __restrict__ alpha, int N) {
    int node = (blockIdx.x * 256 + threadIdx.x) >> 6;
    int lane = threadIdx.x & 63;
    if (node >= N) return;
    int e0 = rowptr[node];
    int deg = degv[node];
    int e1 = e0 + deg;
    float4 ad4 = *(const float4*)&al_d[node * NHEAD];

    if (deg <= 64) {
        float x0 = -INFINITY, x1 = -INFINITY, x2 = -INFINITY, x3 = -INFINITY;
        if (lane < deg) {
            int s = csrc[e0 + lane];
            float4 a = *(const float4*)&al_s[s * NHEAD];
            x0 = a.x + ad4.x; x0 = (x0 > 0.f) ? x0 : NEG_SLOPE * x0;
            x1 = a.y + ad4.y; x1 = (x1 > 0.f) ? x1 : NEG_SLOPE * x1;
            x2 = a.z + ad4.z; x2 = (x2 > 0.f) ? x2 : NEG_SLOPE * x2;
            x3 = a.w + ad4.w; x3 = (x3 > 0.f) ? x3 : NEG_SLOPE * x3;
        }
        float m0 = x0, m1 = x1, m2 = x2, m3 = x3;
#pragma unroll
        for (int off = 32; off; off >>= 1) {
            m0 = fmaxf(m0, __shfl_xor(m0, off));
            m1 = fmaxf(m1, __shfl_xor(m1, off));
            m2 = fmaxf(m2, __shfl_xor(m2, off));
            m3 = fmaxf(m3, __shfl_xor(m3, off));
        }
        float p0 = (lane < deg) ? __expf(x0 - m0) : 0.f;
        float p1 = (lane < deg) ? __expf(x1 - m1) : 0.f;
        float p2 = (lane < deg) ? __expf(x2 - m2) : 0.f;
        float p3 = (lane < deg) ? __expf(x3 - m3) : 0.f;
        float s0 = p0, s1 = p1, s2 = p2, s3 = p3;
#pragma unroll
        for (int off = 32; off; off >>= 1) {
            s0 += __shfl_xor(s0, off);
            s1 += __shfl_xor(s1, off);
            s2 += __shfl_xor(s2, off);
            s3 += __shfl_xor(s3, off);
        }
        if (lane < deg) {
            float4 w;
            w.x = p0 / (s0 + 1e-16f);
            w.y = p1 / (s1 + 1e-16f);
            w.z = p2 / (s2 + 1e-16f);
            w.w = p3 / (s3 + 1e-16f);
            alpha[e0 + lane] = w;
        }
        return;
    }

    float m0 = -INFINITY, m1 = -INFINITY, m2 = -INFINITY, m3 = -INFINITY;
    for (int i = e0 + lane; i < e1; i += 64) {
        int s = csrc[i];
        float4 a = *(const float4*)&al_s[s * NHEAD];
        float e;
        e = a.x + ad4.x; e = (e > 0.f) ? e : NEG_SLOPE * e; m0 = fmaxf(m0, e);
        e = a.y + ad4.y; e = (e > 0.f) ? e : NEG_SLOPE * e; m1 = fmaxf(m1, e);
        e = a.z + ad4.z; e = (e > 0.f) ? e : NEG_SLOPE * e; m2 = fmaxf(m2, e);
        e = a.w + ad4.w; e = (e > 0.f) ? e : NEG_SLOPE * e; m3 = fmaxf(m3, e);
    }
#pragma unroll
    for (int off = 32; off; off >>= 1) {
        m0 = fmaxf(m0, __shfl_xor(m0, off));
        m1 = fmaxf(m1, __shfl_xor(m1, off));
        m2 = fmaxf(m2, __shfl_xor(m2, off));
        m3 = fmaxf(m3, __shfl_xor(m3, off));
    }
    float s0 = 0, s1 = 0, s2 = 0, s3 = 0;
    for (int i = e0 + lane; i < e1; i += 64) {
        int s = csrc[i];
        float4 a = *(const float4*)&al_s[s * NHEAD];
        float e;
        e = a.x + ad4.x; e = (e > 0.f) ? e : NEG_SLOPE * e; s0 += __expf(e - m0);
        e = a.y + ad4.y; e = (e > 0.f) ? e : NEG_SLOPE * e; s1 += __expf(e - m1);
        e = a.z + ad4.z; e = (e > 0.f) ? e : NEG_SLOPE * e; s2 += __expf(e - m2);
        e = a.w + ad4.w; e = (e > 0.f) ? e : NEG_SLOPE * e; s3 += __expf(e - m3);
    }
#pragma unroll
    for (int off = 32; off; off >>= 1) {
        s0 += __shfl_xor(s0, off);
        s1 += __shfl_xor(s1, off);
        s2 += __shfl_xor(s2, off);
        s3 += __shfl_xor(s3, off);
    }
    float r0 = 1.f / (s0 + 1e-16f), r1 = 1.f / (s1 + 1e-16f);
    float r2 = 1.f / (s2 + 1e-16f), r3 = 1.f / (s3 + 1e-16f);
    for (int i = e0 + lane; i < e1; i += 64) {
        int s = csrc[i];
        float4 a = *(const float4*)&al_s[s * NHEAD];
        float4 w;
        float e;
        e = a.x + ad4.x; e = (e > 0.f) ? e : NEG_SLOPE * e; w.x = __expf(e - m0) * r0;
        e = a.y + ad4.y; e = (e > 0.f) ? e : NEG_SLOPE * e; w.y = __expf(e - m1) * r1;
        e = a.z + ad4.z; e = (e > 0.f) ? e : NEG_SLOPE * e; w.z = __expf(e - m2) * r2;
        e = a.w + ad4.w; e = (e > 0.f) ? e : NEG_SLOPE * e; w.w = __expf(e - m3) * r3;
        alpha[i] = w;
    }
}

// ---------------------------------------------------------------------------
// gath: TWO waves per dst node (256 channels each, half4/lane).  Edge range
// padded to x8 -> pure 8-deep load blocks, NO tail (pad alpha = 0).
// +bias, ELU, store fp16.
// ---------------------------------------------------------------------------
__global__ __launch_bounds__(256) void gath_kernel(const _Float16* __restrict__ h16,
                                                   const float4* __restrict__ alpha,
                                                   const int* __restrict__ rowptr,
                                                   const int* __restrict__ degv,
                                                   const int* __restrict__ csrc,
                                                   const float* __restrict__ bias,
                                                   _Float16* __restrict__ out16, int N) {
    int gid = blockIdx.x * 256 + threadIdx.x;
    int wv = gid >> 6, lane = gid & 63;
    int node = wv >> 1, hf = wv & 1;
    if (node >= N) return;
    int e0 = rowptr[node];
    int ee = e0 + ((degv[node] + 7) & ~7);
    size_t cb = (size_t)(hf * 256 + lane * 4);
    bool hiHead = (lane & 32) != 0;

#define PICKW(q) (hf ? (hiHead ? (q).w : (q).z) : (hiHead ? (q).y : (q).x))

    float a0 = 0, a1 = 0, a2 = 0, a3 = 0;
    for (int i = e0; i < ee; i += 8) {
        int sx[8];
        float4 qx[8];
        half4v vx[8];
#pragma unroll
        for (int u = 0; u < 8; ++u) sx[u] = csrc[i + u];
#pragma unroll
        for (int u = 0; u < 8; ++u) qx[u] = alpha[i + u];
#pragma unroll
        for (int u = 0; u < 8; ++u)
            vx[u] = *(const half4v*)(h16 + (size_t)sx[u] * HC + cb);
#pragma unroll
        for (int u = 0; u < 8; ++u) {
            float w = PICKW(qx[u]);
            a0 = fmaf((float)vx[u][0], w, a0);
            a1 = fmaf((float)vx[u][1], w, a1);
            a2 = fmaf((float)vx[u][2], w, a2);
            a3 = fmaf((float)vx[u][3], w, a3);
        }
    }
#undef PICKW

    float4 bb = *(const float4*)&bias[cb];
    a0 += bb.x; a1 += bb.y; a2 += bb.z; a3 += bb.w;
    a0 = (a0 > 0.f) ? a0 : (__expf(a0) - 1.f);
    a1 = (a1 > 0.f) ? a1 : (__expf(a1) - 1.f);
    a2 = (a2 > 0.f) ? a2 : (__expf(a2) - 1.f);
    a3 = (a3 > 0.f) ? a3 : (__expf(a3) - 1.f);
    half4v o = {(_Float16)a0, (_Float16)a1, (_Float16)a2, (_Float16)a3};
    *(half4v*)(out16 + (size_t)node * HC + cb) = o;
}

// ---------------------------------------------------------------------------
// BatchNorm stats stage 1: per-block partials, no atomics.
// ---------------------------------------------------------------------------
__global__ __launch_bounds__(256) void bnstat_kernel(const _Float16* __restrict__ x,
                                                     double* __restrict__ partials,
                                                     int N) {
    __shared__ double lds[2][4][HC];            // 32 KiB
    int t = threadIdx.x;
    int lane = t & 63, wv = t >> 6;
    int c0 = lane * 8;
    const int stride = gridDim.x * 4;

    float s[8] = {}, q[8] = {};
    int r = blockIdx.x * 4 + wv;
    for (; r + stride < N; r += 2 * stride) {
        half8 v0 = *(const half8*)&x[(size_t)r * HC + c0];
        half8 v1 = *(const half8*)&x[(size_t)(r + stride) * HC + c0];
#pragma unroll
        for (int j = 0; j < 8; ++j) {
            float f0 = (float)v0[j], f1 = (float)v1[j];
            s[j] += f0 + f1;
            q[j] = fmaf(f0, f0, q[j]);
            q[j] = fmaf(f1, f1, q[j]);
        }
    }
    for (; r < N; r += stride) {
        half8 v0 = *(const half8*)&x[(size_t)r * HC + c0];
#pragma unroll
        for (int j = 0; j < 8; ++j) {
            float f0 = (float)v0[j];
            s[j] += f0;
            q[j] = fmaf(f0, f0, q[j]);
        }
    }
#pragma unroll
    for (int j = 0; j < 8; ++j) {
        lds[0][wv][c0 + j] = (double)s[j];
        lds[1][wv][c0 + j] = (double)q[j];
    }
    __syncthreads();
    if (wv == 0) {
        double* pb = partials + (size_t)blockIdx.x * 1024;
#pragma unroll
        for (int j = 0; j < 8; ++j) {
            int c = c0 + j;
            pb[c] = lds[0][0][c] + lds[0][1][c] + lds[0][2][c] + lds[0][3][c];
            pb[512 + c] = lds[1][0][c] + lds[1][1][c] + lds[1][2][c] + lds[1][3][c];
        }
    }
}

// ---------------------------------------------------------------------------
// BatchNorm stats stage 2: deterministic cross-block reduce.
// ---------------------------------------------------------------------------
__global__ __launch_bounds__(256) void bnred_kernel(const double* __restrict__ partials,
                                                    double* __restrict__ stats, int nb) {
    int wv = (blockIdx.x * 256 + threadIdx.x) >> 6;
    int lane = threadIdx.x & 63;
    if (wv >= 1024) return;
    double s = 0.0;
    for (int b = lane; b < nb; b += 64)
        s += partials[(size_t)b * 1024 + wv];
#pragma unroll
    for (int off = 32; off; off >>= 1) s += __shfl_xor(s, off);
    if (lane == 0) stats[wv] = s;
}

// ---------------------------------------------------------------------------
// Head: logits = x[N,64] @ w[64,10] + b; log_softmax.  One wave per row.
// ---------------------------------------------------------------------------
__global__ __launch_bounds__(256) void head_kernel(const float* __restrict__ x,
                                                   const float* __restrict__ w,
                                                   const float* __restrict__ b,
                                                   float* __restrict__ out, int N) {
    int wid = (blockIdx.x * 256 + threadIdx.x) >> 6;
    int lane = threadIdx.x & 63;
    if (wid >= N) return;
    float v = x[(size_t)wid * 64 + lane];
    float my = -INFINITY;
#pragma unroll
    for (int j = 0; j < 10; ++j) {
        float t = v * w[lane * 10 + j];
#pragma unroll
        for (int off = 32; off; off >>= 1) t += __shfl_xor(t, off);
        t += b[j];
        if (lane == j) my = t;
    }
    float mx = my;
#pragma unroll
    for (int off = 32; off; off >>= 1) mx = fmaxf(mx, __shfl_xor(mx, off));
    float p = (lane < 10) ? expf(my - mx) : 0.f;
    float sum = p;
#pragma unroll
    for (int off = 32; off; off >>= 1) sum += __shfl_xor(sum, off);
    if (lane < 10) out[(size_t)wid * 10 + lane] = my - mx - logf(sum);
}

// ---------------------------------------------------------------------------
extern "C" void kernel_launch(void* const* d_in, const int* in_sizes, int n_in,
                              void* d_out, int out_size, void* d_ws, size_t ws_size,
                              hipStream_t stream) {
    const float* x = (const float*)d_in[0];
    const int* ei = (const int*)d_in[1];        // [2, E] int32
    const int N = in_sizes[0] / 128;
    const int E = in_sizes[1] / 2;
    const int EN = E + N;
    const int ENP = EN + 8 * N;                 // padded-edge capacity bound
    const int NB_STAT = 256;

    // ---- workspace layout (8B-aligned sections) ----
    double* stats = (double*)d_ws;                               // 1024
    double* partials = stats + 1024;                             // 256*1024
    float* als   = (float*)(partials + (size_t)NB_STAT * 1024);  // N*4
    float* ald   = als + (size_t)N * NHEAD;                      // N*4
    float4* alpha = (float4*)(ald + (size_t)N * NHEAD);          // ENP float4
    float* bvec  = (float*)(alpha + ENP);                        // 512
    float* avec  = bvec + 512;                                   // 512
    float* dvec  = avec + 512;                                   // 512
    float* m1    = dvec + 512;                                   // N*128
    float* m2    = m1 + (size_t)N * 128;                         // N*64
    _Float16* xh   = (_Float16*)(m2 + (size_t)N * 64);           // N*128
    _Float16* h16  = xh + (size_t)N * 128;                       // N*512
    _Float16* out16 = h16 + (size_t)N * HC;                      // N*512
    _Float16* wpool = out16 + (size_t)N * HC;
    _Float16* wthi[4], * wtmhi;
    _Float16* p = wpool;
    wthi[0] = p; p += 512 * 128;
    for (int L = 1; L < 4; ++L) { wthi[L] = p; p += 512 * 512; }
    wtmhi = p; p += 128 * 512;
    int* rowptr = (int*)p;                                       // N+1
    int* wr = rowptr + (N + 1);                                  // N
    int* degv = wr + N;                                          // N
    int* csrc = degv + N;                                        // ENP

    // ---- CSR build (once; padded to x8 per node) ----
    hipMemsetAsync(rowptr, 0, (N + 1) * sizeof(int), stream);
    hipMemsetAsync(csrc, 0, (size_t)ENP * sizeof(int), stream);
    hipMemsetAsync(alpha, 0, (size_t)ENP * sizeof(float4), stream);
    hist_kernel<<<(EN + 255) / 256, 256, 0, stream>>>(ei + E, rowptr, E, N);
    scan_kernel<<<1, 1024, 0, stream>>>(rowptr, wr, degv, N);
    scatter_kernel<<<(EN + 255) / 256, 256, 0, stream>>>(ei, ei + E, wr, csrc, E, N);

    // ---- layer-0 prep ----
    wsplit_kernel<<<dim3(512 / 32, 128 / 32), 256, 0, stream>>>(
        (const float*)d_in[3], nullptr, wthi[0], 128, 512);
    xcvt_kernel<<<1024, 256, 0, stream>>>(x, xh, N * 128);
    hipMemsetAsync(bvec, 0, 512 * sizeof(float), stream);

    const int nodeBlocks = (N * 64 + 255) / 256;
    const int gathBlocks = (N * 128 + 255) / 256;
    const double invN = 1.0 / (double)N;

    for (int L = 0; L < 4; ++L) {
        const float* as_ = (const float*)d_in[4 + 6 * L];
        const float* ad_ = (const float*)d_in[5 + 6 * L];
        const float* b_  = (const float*)d_in[6 + 6 * L];
        const float* g_  = (const float*)d_in[7 + 6 * L];
        const float* bt_ = (const float*)d_in[8 + 6 * L];
        const _Float16* Ain = (L == 0) ? xh : out16;
        const int curK = (L == 0) ? 128 : 512;

        mfma_gemm<0><<<dim3(HC / 128, (N + 127) / 128), 256, 0, stream>>>(
            Ain, wthi[L], bvec, h16, nullptr, N, curK, HC);
        al_kernel<<<nodeBlocks, 256, 0, stream>>>(h16, as_, ad_, als, ald, N);
        attw_kernel<<<nodeBlocks, 256, 0, stream>>>(als, ald, rowptr, degv, csrc,
                                                    alpha, N);
        gath_kernel<<<gathBlocks, 256, 0, stream>>>(h16, alpha, rowptr, degv, csrc,
                                                    b_, out16, N);
        bnstat_kernel<<<NB_STAT, 256, 0, stream>>>(out16, partials, N);
        bnred_kernel<<<256, 256, 0, stream>>>(partials, stats, NB_STAT);
        advec_kernel<<<2, 256, 0, stream>>>(stats, g_, bt_, avec, dvec, invN);

        if (L < 3) {
            const float* Wn = (const float*)d_in[3 + 6 * (L + 1)];
            wsplit_kernel<<<dim3(512 / 32, 512 / 32), 256, 0, stream>>>(
                Wn, avec, wthi[L + 1], 512, 512);
            bvec_kernel<<<(512 * 64 + 255) / 256, 256, 0, stream>>>(
                Wn, dvec, nullptr, bvec, 512, 512);
        } else {
            const float* lw1 = (const float*)d_in[27];
            const float* lb1 = (const float*)d_in[28];
            wsplit_kernel<<<dim3(128 / 32, 512 / 32), 256, 0, stream>>>(
                lw1, avec, wtmhi, 512, 128);
            bvec_kernel<<<(128 * 64 + 255) / 256, 256, 0, stream>>>(
                lw1, dvec, lb1, bvec, 512, 128);
        }
    }

    // ---- MLP head ----
    const float* lw2 = (const float*)d_in[29];
    const float* lb2 = (const float*)d_in[30];
    const float* lw3 = (const float*)d_in[31];
    const float* lb3 = (const float*)d_in[32];

    mfma_gemm<1><<<dim3(1, (N + 127) / 128), 256, 0, stream>>>(
        out16, wtmhi, bvec, nullptr, m1, N, 512, 128);
    gemm_k<64, 64, 16, 4, 4, 1><<<dim3(1, (N + 63) / 64), 256, 0, stream>>>(
        m1, lw2, lb2, m2, N, 128, 64);
    head_kernel<<<nodeBlocks, 256, 0, stream>>>(m2, lw3, lb3, (float*)d_out, N);
}

// Round 12
// 638.380 us; speedup vs baseline: 1.0743x; 1.0743x over previous
//
#include <hip/hip_runtime.h>
#include <hip/hip_bf16.h>
#include <math.h>

#define HC 512
#define NHEAD 4
#define NEG_SLOPE 0.2f
#define EPS_BN 1e-5f

typedef __attribute__((ext_vector_type(8))) _Float16 half8;
typedef __attribute__((ext_vector_type(4))) _Float16 half4v;
typedef __attribute__((ext_vector_type(4))) float f32x4;

#define GLOAD16(gptr, lptr)                                                      \
    __builtin_amdgcn_global_load_lds(                                            \
        (const __attribute__((address_space(1))) unsigned int*)(gptr),           \
        (__attribute__((address_space(3))) unsigned int*)(lptr), 16, 0, 0)

// ---------------------------------------------------------------------------
// CSR build (unpadded).  scatter emits resolved csr_src.  Self-loops j in
// [E,E+N) have src=dst=j-E.
// ---------------------------------------------------------------------------
__global__ void hist_kernel(const int* __restrict__ dstE, int* __restrict__ cnt,
                            int E, int N) {
    int i = blockIdx.x * 256 + threadIdx.x;
    if (i < E + N) {
        int d = (i < E) ? dstE[i] : (i - E);
        atomicAdd(&cnt[d], 1);
    }
}

__global__ __launch_bounds__(1024) void scan_kernel(int* __restrict__ rowptr,
                                                    int* __restrict__ wr, int n) {
    __shared__ int wsum[16];
    __shared__ int carry_s;
    int t = threadIdx.x, lane = t & 63, wv = t >> 6;
    if (t == 0) carry_s = 0;
    __syncthreads();
    for (int base = 0; base < n; base += 1024) {
        int v = (base + t < n) ? rowptr[base + t] : 0;
        int x = v;
#pragma unroll
        for (int off = 1; off < 64; off <<= 1) {
            int y = __shfl_up(x, off);
            if (lane >= off) x += y;
        }
        if (lane == 63) wsum[wv] = x;
        __syncthreads();
        if (wv == 0) {
            int s = (lane < 16) ? wsum[lane] : 0;
#pragma unroll
            for (int off = 1; off < 16; off <<= 1) {
                int y = __shfl_up(s, off);
                if (lane >= off) s += y;
            }
            if (lane < 16) wsum[lane] = s;
        }
        __syncthreads();
        int woff = (wv == 0) ? 0 : wsum[wv - 1];
        int tot = wsum[15];
        int carry = carry_s;
        if (base + t < n) {
            int excl = carry + woff + x - v;
            rowptr[base + t] = excl;
            wr[base + t] = excl;
        }
        __syncthreads();
        if (t == 1023) carry_s = carry + tot;
        __syncthreads();
    }
    if (threadIdx.x == 0) rowptr[n] = carry_s;
}

__global__ void scatter_kernel(const int* __restrict__ srcE,
                               const int* __restrict__ dstE,
                               int* __restrict__ wr, int* __restrict__ csrc,
                               int E, int N) {
    int i = blockIdx.x * 256 + threadIdx.x;
    if (i < E + N) {
        int d = (i < E) ? dstE[i] : (i - E);
        int s = (i < E) ? srcE[i] : (i - E);
        int p = atomicAdd(&wr[d], 1);
        csrc[p] = s;
    }
}

// ---------------------------------------------------------------------------
// BN fold scalars: a_k = g*rsqrt(var+eps), d_k = bt - mu*a  (from double stats)
// ---------------------------------------------------------------------------
__global__ __launch_bounds__(256) void advec_kernel(const double* __restrict__ stats,
                                                    const float* __restrict__ g,
                                                    const float* __restrict__ bt,
                                                    float* __restrict__ avec,
                                                    float* __restrict__ dvec,
                                                    double invN) {
    int k = blockIdx.x * 256 + threadIdx.x;
    if (k >= HC) return;
    double mu = stats[k] * invN;
    double var = stats[HC + k] * invN - mu * mu;
    float a = g[k] * (float)rsqrt(var + (double)EPS_BN);
    avec[k] = a;
    dvec[k] = bt[k] - (float)mu * a;
}

// ---------------------------------------------------------------------------
// Weight transpose + optional per-row scale avec -> fp16.
// ---------------------------------------------------------------------------
__global__ __launch_bounds__(256) void wsplit_kernel(const float* __restrict__ W,
                                                     const float* __restrict__ avec,
                                                     _Float16* __restrict__ hiT,
                                                     int K, int Nc) {
    __shared__ float tile[32][33];
    int bx = blockIdx.x * 32;   // n
    int by = blockIdx.y * 32;   // k
    int tx = threadIdx.x & 31, ty = threadIdx.x >> 5;   // 32 x 8
#pragma unroll
    for (int r = 0; r < 32; r += 8)
        tile[ty + r][tx] = W[(size_t)(by + ty + r) * Nc + bx + tx];
    __syncthreads();
    int k = by + tx;
    float a = avec ? avec[k] : 1.f;
#pragma unroll
    for (int r = 0; r < 32; r += 8) {
        int n = bx + ty + r;
        hiT[(size_t)n * K + k] = (_Float16)(tile[tx][ty + r] * a);
    }
}

// bvec[j] = extra[j] + sum_k dvec[k] * W[k][j]   (one wave per j)
__global__ __launch_bounds__(256) void bvec_kernel(const float* __restrict__ W,
                                                   const float* __restrict__ dvec,
                                                   const float* __restrict__ extra,
                                                   float* __restrict__ bvec,
                                                   int K, int Nc) {
    int wv = (blockIdx.x * 256 + threadIdx.x) >> 6;
    int lane = threadIdx.x & 63;
    if (wv >= Nc) return;
    float s = 0.f;
    for (int k = lane; k < K; k += 64)
        s = fmaf(dvec[k], W[(size_t)k * Nc + wv], s);
#pragma unroll
    for (int off = 32; off; off >>= 1) s += __shfl_xor(s, off);
    if (lane == 0) bvec[wv] = s + (extra ? extra[wv] : 0.f);
}

__global__ __launch_bounds__(256) void xcvt_kernel(const float* __restrict__ x,
                                                   _Float16* __restrict__ xh, int total) {
    for (int i = blockIdx.x * 256 + threadIdx.x; i < total; i += gridDim.x * 256)
        xh[i] = (_Float16)x[i];
}

// ---------------------------------------------------------------------------
// fp16 GEMM: C = A[M,K] @ B[K,Nc] + bvec  (B given transposed [Nc][K]).
// 128x128 tile, BK=32, 2x2 waves, 16x16x32 f16 MFMA, XCD-aware swizzle.
// EPI 0: store fp16 h.  EPI 1: ReLU, store fp32.
// ---------------------------------------------------------------------------
template <int EPI>
__global__ __launch_bounds__(256) void mfma_gemm(const _Float16* __restrict__ A,
                                                 const _Float16* __restrict__ BT,
                                                 const float* __restrict__ bvec,
                                                 _Float16* __restrict__ H16,
                                                 float* __restrict__ C,
                                                 int M, int K, int Nc) {
    __shared__ _Float16 sm[2 * 4096];           // 16 KiB: A | B
    _Float16* sA = sm;
    _Float16* sB = sm + 4096;

    const int nwg = gridDim.x * gridDim.y;
    const int orig = blockIdx.y * gridDim.x + blockIdx.x;
    const int q = nwg >> 3, r = nwg & 7;
    const int xcd = orig & 7, local = orig >> 3;
    const int wgid = (xcd < r ? xcd * (q + 1) : r * (q + 1) + (xcd - r) * q) + local;
    const int bxi = wgid % gridDim.x, byi = wgid / gridDim.x;

    const int tid = threadIdx.x;
    const int wid = tid >> 6, lane = tid & 63;
    const int wm = wid >> 1, wn = wid & 1;      // wave grid 2x2, each 64x64
    const int bm = byi * 128, bn = bxi * 128;

    const int rowl = lane >> 2;
    const int cole = (lane & 3) * 8;
    const int c0 = wid * 2;

    const int frow = lane & 15;
    const int fko = (lane >> 4) * 8;

    f32x4 acc[4][4] = {};

    for (int k0 = 0; k0 < K; k0 += 32) {
#pragma unroll
        for (int cc = 0; cc < 2; ++cc) {
            int c = c0 + cc;
            int ra = bm + c * 16 + rowl; if (ra >= M) ra = M - 1;
            int rb = bn + c * 16 + rowl;
            GLOAD16(A + (size_t)ra * K + k0 + cole, &sA[c * 512]);
            GLOAD16(BT + (size_t)rb * K + k0 + cole, &sB[c * 512]);
        }
        __syncthreads();

        half8 av[4], bv[4];
#pragma unroll
        for (int mi = 0; mi < 4; ++mi) {
            int rr = wm * 64 + mi * 16 + frow;
            av[mi] = *(const half8*)&sA[rr * 32 + fko];
        }
#pragma unroll
        for (int ni = 0; ni < 4; ++ni) {
            int rr = wn * 64 + ni * 16 + frow;
            bv[ni] = *(const half8*)&sB[rr * 32 + fko];
        }
#pragma unroll
        for (int mi = 0; mi < 4; ++mi)
#pragma unroll
            for (int ni = 0; ni < 4; ++ni)
                acc[mi][ni] = __builtin_amdgcn_mfma_f32_16x16x32_f16(av[mi], bv[ni], acc[mi][ni], 0, 0, 0);
        __syncthreads();
    }

    const int crow = (lane >> 4) * 4;
    const int ccol = lane & 15;
#pragma unroll
    for (int mi = 0; mi < 4; ++mi)
#pragma unroll
        for (int ni = 0; ni < 4; ++ni) {
            int gc = bn + wn * 64 + ni * 16 + ccol;
            float bvv = bvec[gc];
#pragma unroll
            for (int rr = 0; rr < 4; ++rr) {
                int gr = bm + wm * 64 + mi * 16 + crow + rr;
                if (gr >= M) continue;
                float v = acc[mi][ni][rr] + bvv;
                if (EPI == 0) {
                    H16[(size_t)gr * Nc + gc] = (_Float16)v;
                } else {
                    C[(size_t)gr * Nc + gc] = fmaxf(v, 0.f);
                }
            }
        }
}

// ---------------------------------------------------------------------------
// Tiled fp32 GEMM (small MLP layer 2).  EPI 1 = +bias, ReLU.
// ---------------------------------------------------------------------------
template <int BM, int BN, int BK, int TM, int TN, int EPI>
__global__ __launch_bounds__(256) void gemm_k(const float* __restrict__ A,
                                              const float* __restrict__ B,
                                              const float* __restrict__ bias,
                                              float* __restrict__ C,
                                              int M, int K, int N) {
    constexpr int PAD = 4;
    __shared__ float sA[BK][BM + PAD];
    __shared__ float sB[BK][BN];

    const int tid = threadIdx.x;
    const int bm = blockIdx.y * BM, bn = blockIdx.x * BN;
    constexpr int TX = BN / TN;
    const int tx = tid % TX, ty = tid / TX;

    float acc[TM][TN] = {};

    constexpr int AF4 = BK / 4;
    const int a4 = tid % AF4;
    const int ar0 = tid / AF4;
    constexpr int AROWS = 256 / AF4;
    constexpr int APASS = BM / AROWS;

    constexpr int BF4 = BN / 4;
    const int b4 = tid % BF4;
    const int br0 = tid / BF4;
    constexpr int BROWS = 256 / BF4;
    constexpr int BPASS = BK / BROWS;

    for (int kt = 0; kt < K; kt += BK) {
        __syncthreads();
#pragma unroll
        for (int p = 0; p < APASS; ++p) {
            int row = ar0 + p * AROWS;
            int gr = bm + row;
            if (gr >= M) gr = M - 1;
            float4 v = *(const float4*)&A[(size_t)gr * K + kt + a4 * 4];
            sA[a4 * 4 + 0][row] = v.x;
            sA[a4 * 4 + 1][row] = v.y;
            sA[a4 * 4 + 2][row] = v.z;
            sA[a4 * 4 + 3][row] = v.w;
        }
#pragma unroll
        for (int p = 0; p < BPASS; ++p) {
            int row = br0 + p * BROWS;
            float4 v = *(const float4*)&B[(size_t)(kt + row) * N + bn + b4 * 4];
            *(float4*)&sB[row][b4 * 4] = v;
        }
        __syncthreads();
#pragma unroll
        for (int k = 0; k < BK; ++k) {
            float ar[TM], br[TN];
#pragma unroll
            for (int i = 0; i < TM; i += 4)
                *(float4*)&ar[i] = *(const float4*)&sA[k][ty * TM + i];
#pragma unroll
            for (int j = 0; j < TN; j += 4)
                *(float4*)&br[j] = *(const float4*)&sB[k][tx * TN + j];
#pragma unroll
            for (int i = 0; i < TM; ++i)
#pragma unroll
                for (int j = 0; j < TN; ++j)
                    acc[i][j] = fmaf(ar[i], br[j], acc[i][j]);
        }
    }

#pragma unroll
    for (int i = 0; i < TM; ++i) {
        int r = bm + ty * TM + i;
        if (r >= M) continue;
#pragma unroll
        for (int j = 0; j < TN; j += 4) {
            int c = bn + tx * TN + j;
            float4 v;
            v.x = acc[i][j + 0]; v.y = acc[i][j + 1];
            v.z = acc[i][j + 2]; v.w = acc[i][j + 3];
            if (EPI == 1) {
                v.x = fmaxf(v.x + bias[c + 0], 0.f);
                v.y = fmaxf(v.y + bias[c + 1], 0.f);
                v.z = fmaxf(v.z + bias[c + 2], 0.f);
                v.w = fmaxf(v.w + bias[c + 3], 0.f);
            }
            *(float4*)&C[(size_t)r * N + c] = v;
        }
    }
}

// ---------------------------------------------------------------------------
// Attention coefficients from fp16 h.  One wave per node.
// ---------------------------------------------------------------------------
__global__ __launch_bounds__(256) void al_kernel(const _Float16* __restrict__ h16,
                                                 const float* __restrict__ asrc,
                                                 const float* __restrict__ adst,
                                                 float* __restrict__ al_s,
                                                 float* __restrict__ al_d, int N) {
    int wid = (blockIdx.x * 256 + threadIdx.x) >> 6;
    int lane = threadIdx.x & 63;
    if (wid >= N) return;
    half8 hv = *(const half8*)(h16 + (size_t)wid * HC + lane * 8);
    float ss = 0.f, sd = 0.f;
#pragma unroll
    for (int j = 0; j < 8; ++j) {
        float v = (float)hv[j];
        ss = fmaf(v, asrc[lane * 8 + j], ss);
        sd = fmaf(v, adst[lane * 8 + j], sd);
    }
#pragma unroll
    for (int off = 8; off; off >>= 1) {
        ss += __shfl_xor(ss, off);
        sd += __shfl_xor(sd, off);
    }
    if ((lane & 15) == 0) {
        al_s[wid * NHEAD + (lane >> 4)] = ss;
        al_d[wid * NHEAD + (lane >> 4)] = sd;
    }
}

// ---------------------------------------------------------------------------
// attw: one wave per dst node.  Fast path (deg<=64): single load pass into
// registers, then max/sumexp/alpha in-register.  Fallback: 3-pass loop.
// ---------------------------------------------------------------------------
__global__ __launch_bounds__(256) void attw_kernel(const float* __restrict__ al_s,
                                                   const float* __restrict__ al_d,
                                                   const int* __restrict__ rowptr,
                                                   const int* __restrict__ csrc,
                                                   float4* __restrict__ alpha, int N) {
    int node = (blockIdx.x * 256 + threadIdx.x) >> 6;
    int lane = threadIdx.x & 63;
    if (node >= N) return;
    int e0 = rowptr[node], e1 = rowptr[node + 1];
    int deg = e1 - e0;
    float4 ad4 = *(const float4*)&al_d[node * NHEAD];

    if (deg <= 64) {
        float x0 = -INFINITY, x1 = -INFINITY, x2 = -INFINITY, x3 = -INFINITY;
        if (lane < deg) {
            int s = csrc[e0 + lane];
            float4 a = *(const float4*)&al_s[s * NHEAD];
            x0 = a.x + ad4.x; x0 = (x0 > 0.f) ? x0 : NEG_SLOPE * x0;
            x1 = a.y + ad4.y; x1 = (x1 > 0.f) ? x1 : NEG_SLOPE * x1;
            x2 = a.z + ad4.z; x2 = (x2 > 0.f) ? x2 : NEG_SLOPE * x2;
            x3 = a.w + ad4.w; x3 = (x3 > 0.f) ? x3 : NEG_SLOPE * x3;
        }
        float m0 = x0, m1 = x1, m2 = x2, m3 = x3;
#pragma unroll
        for (int off = 32; off; off >>= 1) {
            m0 = fmaxf(m0, __shfl_xor(m0, off));
            m1 = fmaxf(m1, __shfl_xor(m1, off));
            m2 = fmaxf(m2, __shfl_xor(m2, off));
            m3 = fmaxf(m3, __shfl_xor(m3, off));
        }
        float p0 = (lane < deg) ? __expf(x0 - m0) : 0.f;
        float p1 = (lane < deg) ? __expf(x1 - m1) : 0.f;
        float p2 = (lane < deg) ? __expf(x2 - m2) : 0.f;
        float p3 = (lane < deg) ? __expf(x3 - m3) : 0.f;
        float s0 = p0, s1 = p1, s2 = p2, s3 = p3;
#pragma unroll
        for (int off = 32; off; off >>= 1) {
            s0 += __shfl_xor(s0, off);
            s1 += __shfl_xor(s1, off);
            s2 += __shfl_xor(s2, off);
            s3 += __shfl_xor(s3, off);
        }
        if (lane < deg) {
            float4 w;
            w.x = p0 / (s0 + 1e-16f);
            w.y = p1 / (s1 + 1e-16f);
            w.z = p2 / (s2 + 1e-16f);
            w.w = p3 / (s3 + 1e-16f);
            alpha[e0 + lane] = w;
        }
        return;
    }

    float m0 = -INFINITY, m1 = -INFINITY, m2 = -INFINITY, m3 = -INFINITY;
    for (int i = e0 + lane; i < e1; i += 64) {
        int s = csrc[i];
        float4 a = *(const float4*)&al_s[s * NHEAD];
        float e;
        e = a.x + ad4.x; e = (e > 0.f) ? e : NEG_SLOPE * e; m0 = fmaxf(m0, e);
        e = a.y + ad4.y; e = (e > 0.f) ? e : NEG_SLOPE * e; m1 = fmaxf(m1, e);
        e = a.z + ad4.z; e = (e > 0.f) ? e : NEG_SLOPE * e; m2 = fmaxf(m2, e);
        e = a.w + ad4.w; e = (e > 0.f) ? e : NEG_SLOPE * e; m3 = fmaxf(m3, e);
    }
#pragma unroll
    for (int off = 32; off; off >>= 1) {
        m0 = fmaxf(m0, __shfl_xor(m0, off));
        m1 = fmaxf(m1, __shfl_xor(m1, off));
        m2 = fmaxf(m2, __shfl_xor(m2, off));
        m3 = fmaxf(m3, __shfl_xor(m3, off));
    }
    float s0 = 0, s1 = 0, s2 = 0, s3 = 0;
    for (int i = e0 + lane; i < e1; i += 64) {
        int s = csrc[i];
        float4 a = *(const float4*)&al_s[s * NHEAD];
        float e;
        e = a.x + ad4.x; e = (e > 0.f) ? e : NEG_SLOPE * e; s0 += __expf(e - m0);
        e = a.y + ad4.y; e = (e > 0.f) ? e : NEG_SLOPE * e; s1 += __expf(e - m1);
        e = a.z + ad4.z; e = (e > 0.f) ? e : NEG_SLOPE * e; s2 += __expf(e - m2);
        e = a.w + ad4.w; e = (e > 0.f) ? e : NEG_SLOPE * e; s3 += __expf(e - m3);
    }
#pragma unroll
    for (int off = 32; off; off >>= 1) {
        s0 += __shfl_xor(s0, off);
        s1 += __shfl_xor(s1, off);
        s2 += __shfl_xor(s2, off);
        s3 += __shfl_xor(s3, off);
    }
    float r0 = 1.f / (s0 + 1e-16f), r1 = 1.f / (s1 + 1e-16f);
    float r2 = 1.f / (s2 + 1e-16f), r3 = 1.f / (s3 + 1e-16f);
    for (int i = e0 + lane; i < e1; i += 64) {
        int s = csrc[i];
        float4 a = *(const float4*)&al_s[s * NHEAD];
        float4 w;
        float e;
        e = a.x + ad4.x; e = (e > 0.f) ? e : NEG_SLOPE * e; w.x = __expf(e - m0) * r0;
        e = a.y + ad4.y; e = (e > 0.f) ? e : NEG_SLOPE * e; w.y = __expf(e - m1) * r1;
        e = a.z + ad4.z; e = (e > 0.f) ? e : NEG_SLOPE * e; w.z = __expf(e - m2) * r2;
        e = a.w + ad4.w; e = (e > 0.f) ? e : NEG_SLOPE * e; w.w = __expf(e - m3) * r3;
        alpha[i] = w;
    }
}

// ---------------------------------------------------------------------------
// gath: TWO waves per dst node (256 channels each, half4/lane), edge loop
// unrolled x4 (4 gathers in flight) + short tail.  +bias, ELU, store fp16.
// [round-9 proven form: 24 VGPR, occupancy ~64%, 49 us]
// ---------------------------------------------------------------------------
__global__ __launch_bounds__(256) void gath_kernel(const _Float16* __restrict__ h16,
                                                   const float4* __restrict__ alpha,
                                                   const int* __restrict__ rowptr,
                                                   const int* __restrict__ csrc,
                                                   const float* __restrict__ bias,
                                                   _Float16* __restrict__ out16, int N) {
    int gid = blockIdx.x * 256 + threadIdx.x;
    int wv = gid >> 6, lane = gid & 63;
    int node = wv >> 1, hf = wv & 1;
    if (node >= N) return;
    int e0 = rowptr[node], e1 = rowptr[node + 1];
    size_t cb = (size_t)(hf * 256 + lane * 4);
    bool hiHead = (lane & 32) != 0;

#define PICKW(q) (hf ? (hiHead ? (q).w : (q).z) : (hiHead ? (q).y : (q).x))

    float a0 = 0, a1 = 0, a2 = 0, a3 = 0;
    int i = e0;
    for (; i + 4 <= e1; i += 4) {
        int s0 = csrc[i], s1 = csrc[i + 1], s2 = csrc[i + 2], s3 = csrc[i + 3];
        float4 q0 = alpha[i], q1 = alpha[i + 1], q2 = alpha[i + 2], q3 = alpha[i + 3];
        half4v v0 = *(const half4v*)(h16 + (size_t)s0 * HC + cb);
        half4v v1 = *(const half4v*)(h16 + (size_t)s1 * HC + cb);
        half4v v2 = *(const half4v*)(h16 + (size_t)s2 * HC + cb);
        half4v v3 = *(const half4v*)(h16 + (size_t)s3 * HC + cb);
        float w0 = PICKW(q0), w1 = PICKW(q1), w2 = PICKW(q2), w3 = PICKW(q3);
        a0 = fmaf((float)v0[0], w0, a0); a1 = fmaf((float)v0[1], w0, a1);
        a2 = fmaf((float)v0[2], w0, a2); a3 = fmaf((float)v0[3], w0, a3);
        a0 = fmaf((float)v1[0], w1, a0); a1 = fmaf((float)v1[1], w1, a1);
        a2 = fmaf((float)v1[2], w1, a2); a3 = fmaf((float)v1[3], w1, a3);
        a0 = fmaf((float)v2[0], w2, a0); a1 = fmaf((float)v2[1], w2, a1);
        a2 = fmaf((float)v2[2], w2, a2); a3 = fmaf((float)v2[3], w2, a3);
        a0 = fmaf((float)v3[0], w3, a0); a1 = fmaf((float)v3[1], w3, a1);
        a2 = fmaf((float)v3[2], w3, a2); a3 = fmaf((float)v3[3], w3, a3);
    }
    for (; i < e1; ++i) {
        int s = csrc[i];
        float4 q = alpha[i];
        float w = PICKW(q);
        half4v v = *(const half4v*)(h16 + (size_t)s * HC + cb);
        a0 = fmaf((float)v[0], w, a0); a1 = fmaf((float)v[1], w, a1);
        a2 = fmaf((float)v[2], w, a2); a3 = fmaf((float)v[3], w, a3);
    }
#undef PICKW

    float4 bb = *(const float4*)&bias[cb];
    a0 += bb.x; a1 += bb.y; a2 += bb.z; a3 += bb.w;
    a0 = (a0 > 0.f) ? a0 : (__expf(a0) - 1.f);
    a1 = (a1 > 0.f) ? a1 : (__expf(a1) - 1.f);
    a2 = (a2 > 0.f) ? a2 : (__expf(a2) - 1.f);
    a3 = (a3 > 0.f) ? a3 : (__expf(a3) - 1.f);
    half4v o = {(_Float16)a0, (_Float16)a1, (_Float16)a2, (_Float16)a3};
    *(half4v*)(out16 + (size_t)node * HC + cb) = o;
}

// ---------------------------------------------------------------------------
// BatchNorm stats stage 1: per-block partials, no atomics.
// ---------------------------------------------------------------------------
__global__ __launch_bounds__(256) void bnstat_kernel(const _Float16* __restrict__ x,
                                                     double* __restrict__ partials,
                                                     int N) {
    __shared__ double lds[2][4][HC];            // 32 KiB
    int t = threadIdx.x;
    int lane = t & 63, wv = t >> 6;
    int c0 = lane * 8;
    const int stride = gridDim.x * 4;

    float s[8] = {}, q[8] = {};
    int r = blockIdx.x * 4 + wv;
    for (; r + stride < N; r += 2 * stride) {
        half8 v0 = *(const half8*)&x[(size_t)r * HC + c0];
        half8 v1 = *(const half8*)&x[(size_t)(r + stride) * HC + c0];
#pragma unroll
        for (int j = 0; j < 8; ++j) {
            float f0 = (float)v0[j], f1 = (float)v1[j];
            s[j] += f0 + f1;
            q[j] = fmaf(f0, f0, q[j]);
            q[j] = fmaf(f1, f1, q[j]);
        }
    }
    for (; r < N; r += stride) {
        half8 v0 = *(const half8*)&x[(size_t)r * HC + c0];
#pragma unroll
        for (int j = 0; j < 8; ++j) {
            float f0 = (float)v0[j];
            s[j] += f0;
            q[j] = fmaf(f0, f0, q[j]);
        }
    }
#pragma unroll
    for (int j = 0; j < 8; ++j) {
        lds[0][wv][c0 + j] = (double)s[j];
        lds[1][wv][c0 + j] = (double)q[j];
    }
    __syncthreads();
    if (wv == 0) {
        double* pb = partials + (size_t)blockIdx.x * 1024;
#pragma unroll
        for (int j = 0; j < 8; ++j) {
            int c = c0 + j;
            pb[c] = lds[0][0][c] + lds[0][1][c] + lds[0][2][c] + lds[0][3][c];
            pb[512 + c] = lds[1][0][c] + lds[1][1][c] + lds[1][2][c] + lds[1][3][c];
        }
    }
}

// ---------------------------------------------------------------------------
// BatchNorm stats stage 2: deterministic cross-block reduce.
// ---------------------------------------------------------------------------
__global__ __launch_bounds__(256) void bnred_kernel(const double* __restrict__ partials,
                                                    double* __restrict__ stats, int nb) {
    int wv = (blockIdx.x * 256 + threadIdx.x) >> 6;
    int lane = threadIdx.x & 63;
    if (wv >= 1024) return;
    double s = 0.0;
    for (int b = lane; b < nb; b += 64)
        s += partials[(size_t)b * 1024 + wv];
#pragma unroll
    for (int off = 32; off; off >>= 1) s += __shfl_xor(s, off);
    if (lane == 0) stats[wv] = s;
}

// ---------------------------------------------------------------------------
// Head: logits = x[N,64] @ w[64,10] + b; log_softmax.  One wave per row.
// ---------------------------------------------------------------------------
__global__ __launch_bounds__(256) void head_kernel(const float* __restrict__ x,
                                                   const float* __restrict__ w,
                                                   const float* __restrict__ b,
                                                   float* __restrict__ out, int N) {
    int wid = (blockIdx.x * 256 + threadIdx.x) >> 6;
    int lane = threadIdx.x & 63;
    if (wid >= N) return;
    float v = x[(size_t)wid * 64 + lane];
    float my = -INFINITY;
#pragma unroll
    for (int j = 0; j < 10; ++j) {
        float t = v * w[lane * 10 + j];
#pragma unroll
        for (int off = 32; off; off >>= 1) t += __shfl_xor(t, off);
        t += b[j];
        if (lane == j) my = t;
    }
    float mx = my;
#pragma unroll
    for (int off = 32; off; off >>= 1) mx = fmaxf(mx, __shfl_xor(mx, off));
    float p = (lane < 10) ? expf(my - mx) : 0.f;
    float sum = p;
#pragma unroll
    for (int off = 32; off; off >>= 1) sum += __shfl_xor(sum, off);
    if (lane < 10) out[(size_t)wid * 10 + lane] = my - mx - logf(sum);
}

// ---------------------------------------------------------------------------
extern "C" void kernel_launch(void* const* d_in, const int* in_sizes, int n_in,
                              void* d_out, int out_size, void* d_ws, size_t ws_size,
                              hipStream_t stream) {
    const float* x = (const float*)d_in[0];
    const int* ei = (const int*)d_in[1];        // [2, E] int32
    const int N = in_sizes[0] / 128;
    const int E = in_sizes[1] / 2;
    const int EN = E + N;
    const int NB_STAT = 256;

    // ---- workspace layout (8B-aligned sections) ----
    double* stats = (double*)d_ws;                               // 1024
    double* partials = stats + 1024;                             // 256*1024
    float* als   = (float*)(partials + (size_t)NB_STAT * 1024);  // N*4
    float* ald   = als + (size_t)N * NHEAD;                      // N*4
    float4* alpha = (float4*)(ald + (size_t)N * NHEAD);          // EN float4
    float* bvec  = (float*)(alpha + EN);                         // 512
    float* avec  = bvec + 512;                                   // 512
    float* dvec  = avec + 512;                                   // 512
    float* m1    = dvec + 512;                                   // N*128
    float* m2    = m1 + (size_t)N * 128;                         // N*64
    _Float16* xh   = (_Float16*)(m2 + (size_t)N * 64);           // N*128
    _Float16* h16  = xh + (size_t)N * 128;                       // N*512
    _Float16* out16 = h16 + (size_t)N * HC;                      // N*512
    _Float16* wpool = out16 + (size_t)N * HC;
    _Float16* wthi[4], * wtmhi;
    _Float16* p = wpool;
    wthi[0] = p; p += 512 * 128;
    for (int L = 1; L < 4; ++L) { wthi[L] = p; p += 512 * 512; }
    wtmhi = p; p += 128 * 512;
    int* rowptr = (int*)p;                                       // N+1
    int* wr = rowptr + (N + 1);                                  // N
    int* csrc = wr + N;                                          // EN

    // ---- CSR build (once) ----
    hipMemsetAsync(rowptr, 0, (N + 1) * sizeof(int), stream);
    hist_kernel<<<(EN + 255) / 256, 256, 0, stream>>>(ei + E, rowptr, E, N);
    scan_kernel<<<1, 1024, 0, stream>>>(rowptr, wr, N);
    scatter_kernel<<<(EN + 255) / 256, 256, 0, stream>>>(ei, ei + E, wr, csrc, E, N);

    // ---- layer-0 prep ----
    wsplit_kernel<<<dim3(512 / 32, 128 / 32), 256, 0, stream>>>(
        (const float*)d_in[3], nullptr, wthi[0], 128, 512);
    xcvt_kernel<<<1024, 256, 0, stream>>>(x, xh, N * 128);
    hipMemsetAsync(bvec, 0, 512 * sizeof(float), stream);

    const int nodeBlocks = (N * 64 + 255) / 256;
    const int gathBlocks = (N * 128 + 255) / 256;
    const double invN = 1.0 / (double)N;

    for (int L = 0; L < 4; ++L) {
        const float* as_ = (const float*)d_in[4 + 6 * L];
        const float* ad_ = (const float*)d_in[5 + 6 * L];
        const float* b_  = (const float*)d_in[6 + 6 * L];
        const float* g_  = (const float*)d_in[7 + 6 * L];
        const float* bt_ = (const float*)d_in[8 + 6 * L];
        const _Float16* Ain = (L == 0) ? xh : out16;
        const int curK = (L == 0) ? 128 : 512;

        mfma_gemm<0><<<dim3(HC / 128, (N + 127) / 128), 256, 0, stream>>>(
            Ain, wthi[L], bvec, h16, nullptr, N, curK, HC);
        al_kernel<<<nodeBlocks, 256, 0, stream>>>(h16, as_, ad_, als, ald, N);
        attw_kernel<<<nodeBlocks, 256, 0, stream>>>(als, ald, rowptr, csrc, alpha, N);
        gath_kernel<<<gathBlocks, 256, 0, stream>>>(h16, alpha, rowptr, csrc, b_,
                                                    out16, N);
        bnstat_kernel<<<NB_STAT, 256, 0, stream>>>(out16, partials, N);
        bnred_kernel<<<256, 256, 0, stream>>>(partials, stats, NB_STAT);
        advec_kernel<<<2, 256, 0, stream>>>(stats, g_, bt_, avec, dvec, invN);

        if (L < 3) {
            const float* Wn = (const float*)d_in[3 + 6 * (L + 1)];
            wsplit_kernel<<<dim3(512 / 32, 512 / 32), 256, 0, stream>>>(
                Wn, avec, wthi[L + 1], 512, 512);
            bvec_kernel<<<(512 * 64 + 255) / 256, 256, 0, stream>>>(
                Wn, dvec, nullptr, bvec, 512, 512);
        } else {
            const float* lw1 = (const float*)d_in[27];
            const float* lb1 = (const float*)d_in[28];
            wsplit_kernel<<<dim3(128 / 32, 512 / 32), 256, 0, stream>>>(
                lw1, avec, wtmhi, 512, 128);
            bvec_kernel<<<(128 * 64 + 255) / 256, 256, 0, stream>>>(
                lw1, dvec, lb1, bvec, 512, 128);
        }
    }

    // ---- MLP head ----
    const float* lw2 = (const float*)d_in[29];
    const float* lb2 = (const float*)d_in[30];
    const float* lw3 = (const float*)d_in[31];
    const float* lb3 = (const float*)d_in[32];

    mfma_gemm<1><<<dim3(1, (N + 127) / 128), 256, 0, stream>>>(
        out16, wtmhi, bvec, nullptr, m1, N, 512, 128);
    gemm_k<64, 64, 16, 4, 4, 1><<<dim3(1, (N + 63) / 64), 256, 0, stream>>>(
        m1, lw2, lb2, m2, N, 128, 64);
    head_kernel<<<nodeBlocks, 256, 0, stream>>>(m2, lw3, lb3, (float*)d_out, N);
}

// Round 13
// 594.292 us; speedup vs baseline: 1.1540x; 1.0742x over previous
//
#include <hip/hip_runtime.h>
#include <hip/hip_bf16.h>
#include <math.h>

#define HC 512
#define NHEAD 4
#define NEG_SLOPE 0.2f
#define EPS_BN 1e-5f

typedef __attribute__((ext_vector_type(8))) _Float16 half8;
typedef __attribute__((ext_vector_type(4))) _Float16 half4v;
typedef __attribute__((ext_vector_type(4))) float f32x4;

#define GLOAD16(gptr, lptr)                                                      \
    __builtin_amdgcn_global_load_lds(                                            \
        (const __attribute__((address_space(1))) unsigned int*)(gptr),           \
        (__attribute__((address_space(3))) unsigned int*)(lptr), 16, 0, 0)

// ---------------------------------------------------------------------------
// CSR build (unpadded).  scatter emits resolved csr_src.  Self-loops j in
// [E,E+N) have src=dst=j-E.
// ---------------------------------------------------------------------------
__global__ void hist_kernel(const int* __restrict__ dstE, int* __restrict__ cnt,
                            int E, int N) {
    int i = blockIdx.x * 256 + threadIdx.x;
    if (i < E + N) {
        int d = (i < E) ? dstE[i] : (i - E);
        atomicAdd(&cnt[d], 1);
    }
}

__global__ __launch_bounds__(1024) void scan_kernel(int* __restrict__ rowptr,
                                                    int* __restrict__ wr, int n) {
    __shared__ int wsum[16];
    __shared__ int carry_s;
    int t = threadIdx.x, lane = t & 63, wv = t >> 6;
    if (t == 0) carry_s = 0;
    __syncthreads();
    for (int base = 0; base < n; base += 1024) {
        int v = (base + t < n) ? rowptr[base + t] : 0;
        int x = v;
#pragma unroll
        for (int off = 1; off < 64; off <<= 1) {
            int y = __shfl_up(x, off);
            if (lane >= off) x += y;
        }
        if (lane == 63) wsum[wv] = x;
        __syncthreads();
        if (wv == 0) {
            int s = (lane < 16) ? wsum[lane] : 0;
#pragma unroll
            for (int off = 1; off < 16; off <<= 1) {
                int y = __shfl_up(s, off);
                if (lane >= off) s += y;
            }
            if (lane < 16) wsum[lane] = s;
        }
        __syncthreads();
        int woff = (wv == 0) ? 0 : wsum[wv - 1];
        int tot = wsum[15];
        int carry = carry_s;
        if (base + t < n) {
            int excl = carry + woff + x - v;
            rowptr[base + t] = excl;
            wr[base + t] = excl;
        }
        __syncthreads();
        if (t == 1023) carry_s = carry + tot;
        __syncthreads();
    }
    if (threadIdx.x == 0) rowptr[n] = carry_s;
}

__global__ void scatter_kernel(const int* __restrict__ srcE,
                               const int* __restrict__ dstE,
                               int* __restrict__ wr, int* __restrict__ csrc,
                               int E, int N) {
    int i = blockIdx.x * 256 + threadIdx.x;
    if (i < E + N) {
        int d = (i < E) ? dstE[i] : (i - E);
        int s = (i < E) ? srcE[i] : (i - E);
        int p = atomicAdd(&wr[d], 1);
        csrc[p] = s;
    }
}

// ---------------------------------------------------------------------------
// Weight transpose + optional per-row scale avec -> fp16.
// ---------------------------------------------------------------------------
__global__ __launch_bounds__(256) void wsplit_kernel(const float* __restrict__ W,
                                                     const float* __restrict__ avec,
                                                     _Float16* __restrict__ hiT,
                                                     int K, int Nc) {
    __shared__ float tile[32][33];
    int bx = blockIdx.x * 32;   // n
    int by = blockIdx.y * 32;   // k
    int tx = threadIdx.x & 31, ty = threadIdx.x >> 5;   // 32 x 8
#pragma unroll
    for (int r = 0; r < 32; r += 8)
        tile[ty + r][tx] = W[(size_t)(by + ty + r) * Nc + bx + tx];
    __syncthreads();
    int k = by + tx;
    float a = avec ? avec[k] : 1.f;
#pragma unroll
    for (int r = 0; r < 32; r += 8) {
        int n = bx + ty + r;
        hiT[(size_t)n * K + k] = (_Float16)(tile[tx][ty + r] * a);
    }
}

// bvec[j] = extra[j] + sum_k dvec[k] * W[k][j]   (one wave per j)
__global__ __launch_bounds__(256) void bvec_kernel(const float* __restrict__ W,
                                                   const float* __restrict__ dvec,
                                                   const float* __restrict__ extra,
                                                   float* __restrict__ bvec,
                                                   int K, int Nc) {
    int wv = (blockIdx.x * 256 + threadIdx.x) >> 6;
    int lane = threadIdx.x & 63;
    if (wv >= Nc) return;
    float s = 0.f;
    for (int k = lane; k < K; k += 64)
        s = fmaf(dvec[k], W[(size_t)k * Nc + wv], s);
#pragma unroll
    for (int off = 32; off; off >>= 1) s += __shfl_xor(s, off);
    if (lane == 0) bvec[wv] = s + (extra ? extra[wv] : 0.f);
}

__global__ __launch_bounds__(256) void xcvt_kernel(const float* __restrict__ x,
                                                   _Float16* __restrict__ xh, int total) {
    for (int i = blockIdx.x * 256 + threadIdx.x; i < total; i += gridDim.x * 256)
        xh[i] = (_Float16)x[i];
}

// ---------------------------------------------------------------------------
// fp16 GEMM: C = A[M,K] @ B[K,Nc] + bvec  (B given transposed [Nc][K]).
// 128x128 tile, BK=32, 2x2 waves, 16x16x32 f16 MFMA, XCD-aware swizzle.
// EPI 0: store fp16 h.  EPI 1: ReLU, store fp32.
// ---------------------------------------------------------------------------
template <int EPI>
__global__ __launch_bounds__(256) void mfma_gemm(const _Float16* __restrict__ A,
                                                 const _Float16* __restrict__ BT,
                                                 const float* __restrict__ bvec,
                                                 _Float16* __restrict__ H16,
                                                 float* __restrict__ C,
                                                 int M, int K, int Nc) {
    __shared__ _Float16 sm[2 * 4096];           // 16 KiB: A | B
    _Float16* sA = sm;
    _Float16* sB = sm + 4096;

    const int nwg = gridDim.x * gridDim.y;
    const int orig = blockIdx.y * gridDim.x + blockIdx.x;
    const int q = nwg >> 3, r = nwg & 7;
    const int xcd = orig & 7, local = orig >> 3;
    const int wgid = (xcd < r ? xcd * (q + 1) : r * (q + 1) + (xcd - r) * q) + local;
    const int bxi = wgid % gridDim.x, byi = wgid / gridDim.x;

    const int tid = threadIdx.x;
    const int wid = tid >> 6, lane = tid & 63;
    const int wm = wid >> 1, wn = wid & 1;      // wave grid 2x2, each 64x64
    const int bm = byi * 128, bn = bxi * 128;

    const int rowl = lane >> 2;
    const int cole = (lane & 3) * 8;
    const int c0 = wid * 2;

    const int frow = lane & 15;
    const int fko = (lane >> 4) * 8;

    f32x4 acc[4][4] = {};

    for (int k0 = 0; k0 < K; k0 += 32) {
#pragma unroll
        for (int cc = 0; cc < 2; ++cc) {
            int c = c0 + cc;
            int ra = bm + c * 16 + rowl; if (ra >= M) ra = M - 1;
            int rb = bn + c * 16 + rowl;
            GLOAD16(A + (size_t)ra * K + k0 + cole, &sA[c * 512]);
            GLOAD16(BT + (size_t)rb * K + k0 + cole, &sB[c * 512]);
        }
        __syncthreads();

        half8 av[4], bv[4];
#pragma unroll
        for (int mi = 0; mi < 4; ++mi) {
            int rr = wm * 64 + mi * 16 + frow;
            av[mi] = *(const half8*)&sA[rr * 32 + fko];
        }
#pragma unroll
        for (int ni = 0; ni < 4; ++ni) {
            int rr = wn * 64 + ni * 16 + frow;
            bv[ni] = *(const half8*)&sB[rr * 32 + fko];
        }
#pragma unroll
        for (int mi = 0; mi < 4; ++mi)
#pragma unroll
            for (int ni = 0; ni < 4; ++ni)
                acc[mi][ni] = __builtin_amdgcn_mfma_f32_16x16x32_f16(av[mi], bv[ni], acc[mi][ni], 0, 0, 0);
        __syncthreads();
    }

    const int crow = (lane >> 4) * 4;
    const int ccol = lane & 15;
#pragma unroll
    for (int mi = 0; mi < 4; ++mi)
#pragma unroll
        for (int ni = 0; ni < 4; ++ni) {
            int gc = bn + wn * 64 + ni * 16 + ccol;
            float bvv = bvec[gc];
#pragma unroll
            for (int rr = 0; rr < 4; ++rr) {
                int gr = bm + wm * 64 + mi * 16 + crow + rr;
                if (gr >= M) continue;
                float v = acc[mi][ni][rr] + bvv;
                if (EPI == 0) {
                    H16[(size_t)gr * Nc + gc] = (_Float16)v;
                } else {
                    C[(size_t)gr * Nc + gc] = fmaxf(v, 0.f);
                }
            }
        }
}

// ---------------------------------------------------------------------------
// Tiled fp32 GEMM (small MLP layer 2).  EPI 1 = +bias, ReLU.
// ---------------------------------------------------------------------------
template <int BM, int BN, int BK, int TM, int TN, int EPI>
__global__ __launch_bounds__(256) void gemm_k(const float* __restrict__ A,
                                              const float* __restrict__ B,
                                              const float* __restrict__ bias,
                                              float* __restrict__ C,
                                              int M, int K, int N) {
    constexpr int PAD = 4;
    __shared__ float sA[BK][BM + PAD];
    __shared__ float sB[BK][BN];

    const int tid = threadIdx.x;
    const int bm = blockIdx.y * BM, bn = blockIdx.x * BN;
    constexpr int TX = BN / TN;
    const int tx = tid % TX, ty = tid / TX;

    float acc[TM][TN] = {};

    constexpr int AF4 = BK / 4;
    const int a4 = tid % AF4;
    const int ar0 = tid / AF4;
    constexpr int AROWS = 256 / AF4;
    constexpr int APASS = BM / AROWS;

    constexpr int BF4 = BN / 4;
    const int b4 = tid % BF4;
    const int br0 = tid / BF4;
    constexpr int BROWS = 256 / BF4;
    constexpr int BPASS = BK / BROWS;

    for (int kt = 0; kt < K; kt += BK) {
        __syncthreads();
#pragma unroll
        for (int p = 0; p < APASS; ++p) {
            int row = ar0 + p * AROWS;
            int gr = bm + row;
            if (gr >= M) gr = M - 1;
            float4 v = *(const float4*)&A[(size_t)gr * K + kt + a4 * 4];
            sA[a4 * 4 + 0][row] = v.x;
            sA[a4 * 4 + 1][row] = v.y;
            sA[a4 * 4 + 2][row] = v.z;
            sA[a4 * 4 + 3][row] = v.w;
        }
#pragma unroll
        for (int p = 0; p < BPASS; ++p) {
            int row = br0 + p * BROWS;
            float4 v = *(const float4*)&B[(size_t)(kt + row) * N + bn + b4 * 4];
            *(float4*)&sB[row][b4 * 4] = v;
        }
        __syncthreads();
#pragma unroll
        for (int k = 0; k < BK; ++k) {
            float ar[TM], br[TN];
#pragma unroll
            for (int i = 0; i < TM; i += 4)
                *(float4*)&ar[i] = *(const float4*)&sA[k][ty * TM + i];
#pragma unroll
            for (int j = 0; j < TN; j += 4)
                *(float4*)&br[j] = *(const float4*)&sB[k][tx * TN + j];
#pragma unroll
            for (int i = 0; i < TM; ++i)
#pragma unroll
                for (int j = 0; j < TN; ++j)
                    acc[i][j] = fmaf(ar[i], br[j], acc[i][j]);
        }
    }

#pragma unroll
    for (int i = 0; i < TM; ++i) {
        int r = bm + ty * TM + i;
        if (r >= M) continue;
#pragma unroll
        for (int j = 0; j < TN; j += 4) {
            int c = bn + tx * TN + j;
            float4 v;
            v.x = acc[i][j + 0]; v.y = acc[i][j + 1];
            v.z = acc[i][j + 2]; v.w = acc[i][j + 3];
            if (EPI == 1) {
                v.x = fmaxf(v.x + bias[c + 0], 0.f);
                v.y = fmaxf(v.y + bias[c + 1], 0.f);
                v.z = fmaxf(v.z + bias[c + 2], 0.f);
                v.w = fmaxf(v.w + bias[c + 3], 0.f);
            }
            *(float4*)&C[(size_t)r * N + c] = v;
        }
    }
}

// ---------------------------------------------------------------------------
// Attention coefficients from fp16 h.  One wave per node.
// ---------------------------------------------------------------------------
__global__ __launch_bounds__(256) void al_kernel(const _Float16* __restrict__ h16,
                                                 const float* __restrict__ asrc,
                                                 const float* __restrict__ adst,
                                                 float* __restrict__ al_s,
                                                 float* __restrict__ al_d, int N) {
    int wid = (blockIdx.x * 256 + threadIdx.x) >> 6;
    int lane = threadIdx.x & 63;
    if (wid >= N) return;
    half8 hv = *(const half8*)(h16 + (size_t)wid * HC + lane * 8);
    float ss = 0.f, sd = 0.f;
#pragma unroll
    for (int j = 0; j < 8; ++j) {
        float v = (float)hv[j];
        ss = fmaf(v, asrc[lane * 8 + j], ss);
        sd = fmaf(v, adst[lane * 8 + j], sd);
    }
#pragma unroll
    for (int off = 8; off; off >>= 1) {
        ss += __shfl_xor(ss, off);
        sd += __shfl_xor(sd, off);
    }
    if ((lane & 15) == 0) {
        al_s[wid * NHEAD + (lane >> 4)] = ss;
        al_d[wid * NHEAD + (lane >> 4)] = sd;
    }
}

// ---------------------------------------------------------------------------
// attgath: FUSED softmax + gather.  2 waves per node (2 nodes per block).
// Phase 1 (wave hf=0): one-pass in-register softmax (deg<=64), alpha -> LDS;
// deg>64 fallback: 3-pass, alpha -> global galpha.  __syncthreads.
// Phase 2 (both waves): unroll-4 weighted gather of h16 (identical to the
// proven gath loop), alpha from LDS (4B/edge, broadcast) or galpha.
// +bias, ELU, store fp16.
// ---------------------------------------------------------------------------
__global__ __launch_bounds__(256) void attgath_kernel(const _Float16* __restrict__ h16,
                                                      const float* __restrict__ al_s,
                                                      const float* __restrict__ al_d,
                                                      const int* __restrict__ rowptr,
                                                      const int* __restrict__ csrc,
                                                      float4* __restrict__ galpha,
                                                      const float* __restrict__ bias,
                                                      _Float16* __restrict__ out16,
                                                      int N) {
    __shared__ float4 lal[2][64];               // 2 KiB alpha staging
    int gid = blockIdx.x * 256 + threadIdx.x;
    int wv = gid >> 6, lane = gid & 63;
    int node = wv >> 1, hf = wv & 1;
    int slot = (threadIdx.x >> 7);              // node slot within block (0/1)
    bool valid = node < N;
    int e0 = 0, deg = 0;
    if (valid) {
        e0 = rowptr[node];
        deg = rowptr[node + 1] - e0;
    }

    // ---- phase 1: softmax (wave hf==0 of each node) ----
    if (valid && hf == 0) {
        float4 ad4 = *(const float4*)&al_d[node * NHEAD];
        if (deg <= 64) {
            float x0 = -INFINITY, x1 = -INFINITY, x2 = -INFINITY, x3 = -INFINITY;
            if (lane < deg) {
                int s = csrc[e0 + lane];
                float4 a = *(const float4*)&al_s[s * NHEAD];
                x0 = a.x + ad4.x; x0 = (x0 > 0.f) ? x0 : NEG_SLOPE * x0;
                x1 = a.y + ad4.y; x1 = (x1 > 0.f) ? x1 : NEG_SLOPE * x1;
                x2 = a.z + ad4.z; x2 = (x2 > 0.f) ? x2 : NEG_SLOPE * x2;
                x3 = a.w + ad4.w; x3 = (x3 > 0.f) ? x3 : NEG_SLOPE * x3;
            }
            float m0 = x0, m1 = x1, m2 = x2, m3 = x3;
#pragma unroll
            for (int off = 32; off; off >>= 1) {
                m0 = fmaxf(m0, __shfl_xor(m0, off));
                m1 = fmaxf(m1, __shfl_xor(m1, off));
                m2 = fmaxf(m2, __shfl_xor(m2, off));
                m3 = fmaxf(m3, __shfl_xor(m3, off));
            }
            float p0 = (lane < deg) ? __expf(x0 - m0) : 0.f;
            float p1 = (lane < deg) ? __expf(x1 - m1) : 0.f;
            float p2 = (lane < deg) ? __expf(x2 - m2) : 0.f;
            float p3 = (lane < deg) ? __expf(x3 - m3) : 0.f;
            float s0 = p0, s1 = p1, s2 = p2, s3 = p3;
#pragma unroll
            for (int off = 32; off; off >>= 1) {
                s0 += __shfl_xor(s0, off);
                s1 += __shfl_xor(s1, off);
                s2 += __shfl_xor(s2, off);
                s3 += __shfl_xor(s3, off);
            }
            if (lane < deg) {
                float4 w;
                w.x = p0 / (s0 + 1e-16f);
                w.y = p1 / (s1 + 1e-16f);
                w.z = p2 / (s2 + 1e-16f);
                w.w = p3 / (s3 + 1e-16f);
                lal[slot][lane] = w;
            }
        } else {
            int e1 = e0 + deg;
            float m0 = -INFINITY, m1 = -INFINITY, m2 = -INFINITY, m3 = -INFINITY;
            for (int i = e0 + lane; i < e1; i += 64) {
                int s = csrc[i];
                float4 a = *(const float4*)&al_s[s * NHEAD];
                float e;
                e = a.x + ad4.x; e = (e > 0.f) ? e : NEG_SLOPE * e; m0 = fmaxf(m0, e);
                e = a.y + ad4.y; e = (e > 0.f) ? e : NEG_SLOPE * e; m1 = fmaxf(m1, e);
                e = a.z + ad4.z; e = (e > 0.f) ? e : NEG_SLOPE * e; m2 = fmaxf(m2, e);
                e = a.w + ad4.w; e = (e > 0.f) ? e : NEG_SLOPE * e; m3 = fmaxf(m3, e);
            }
#pragma unroll
            for (int off = 32; off; off >>= 1) {
                m0 = fmaxf(m0, __shfl_xor(m0, off));
                m1 = fmaxf(m1, __shfl_xor(m1, off));
                m2 = fmaxf(m2, __shfl_xor(m2, off));
                m3 = fmaxf(m3, __shfl_xor(m3, off));
            }
            float s0 = 0, s1 = 0, s2 = 0, s3 = 0;
            for (int i = e0 + lane; i < e1; i += 64) {
                int s = csrc[i];
                float4 a = *(const float4*)&al_s[s * NHEAD];
                float e;
                e = a.x + ad4.x; e = (e > 0.f) ? e : NEG_SLOPE * e; s0 += __expf(e - m0);
                e = a.y + ad4.y; e = (e > 0.f) ? e : NEG_SLOPE * e; s1 += __expf(e - m1);
                e = a.z + ad4.z; e = (e > 0.f) ? e : NEG_SLOPE * e; s2 += __expf(e - m2);
                e = a.w + ad4.w; e = (e > 0.f) ? e : NEG_SLOPE * e; s3 += __expf(e - m3);
            }
#pragma unroll
            for (int off = 32; off; off >>= 1) {
                s0 += __shfl_xor(s0, off);
                s1 += __shfl_xor(s1, off);
                s2 += __shfl_xor(s2, off);
                s3 += __shfl_xor(s3, off);
            }
            float r0 = 1.f / (s0 + 1e-16f), r1 = 1.f / (s1 + 1e-16f);
            float r2 = 1.f / (s2 + 1e-16f), r3 = 1.f / (s3 + 1e-16f);
            for (int i = e0 + lane; i < e1; i += 64) {
                int s = csrc[i];
                float4 a = *(const float4*)&al_s[s * NHEAD];
                float4 w;
                float e;
                e = a.x + ad4.x; e = (e > 0.f) ? e : NEG_SLOPE * e; w.x = __expf(e - m0) * r0;
                e = a.y + ad4.y; e = (e > 0.f) ? e : NEG_SLOPE * e; w.y = __expf(e - m1) * r1;
                e = a.z + ad4.z; e = (e > 0.f) ? e : NEG_SLOPE * e; w.z = __expf(e - m2) * r2;
                e = a.w + ad4.w; e = (e > 0.f) ? e : NEG_SLOPE * e; w.w = __expf(e - m3) * r3;
                galpha[i] = w;
            }
        }
    }
    __syncthreads();
    if (!valid) return;

    // ---- phase 2: weighted gather (both waves) ----
    size_t cb = (size_t)(hf * 256 + lane * 4);
    bool hiHead = (lane & 32) != 0;
    int comp = hf * 2 + (hiHead ? 1 : 0);
    const float* lap = (const float*)&lal[slot][0] + comp;   // stride 4 floats/edge

    float a0 = 0, a1 = 0, a2 = 0, a3 = 0;
    if (deg <= 64) {
        int i = 0;
        for (; i + 4 <= deg; i += 4) {
            int s0 = csrc[e0 + i], s1 = csrc[e0 + i + 1];
            int s2 = csrc[e0 + i + 2], s3 = csrc[e0 + i + 3];
            float w0 = lap[4 * i], w1 = lap[4 * (i + 1)];
            float w2 = lap[4 * (i + 2)], w3 = lap[4 * (i + 3)];
            half4v v0 = *(const half4v*)(h16 + (size_t)s0 * HC + cb);
            half4v v1 = *(const half4v*)(h16 + (size_t)s1 * HC + cb);
            half4v v2 = *(const half4v*)(h16 + (size_t)s2 * HC + cb);
            half4v v3 = *(const half4v*)(h16 + (size_t)s3 * HC + cb);
            a0 = fmaf((float)v0[0], w0, a0); a1 = fmaf((float)v0[1], w0, a1);
            a2 = fmaf((float)v0[2], w0, a2); a3 = fmaf((float)v0[3], w0, a3);
            a0 = fmaf((float)v1[0], w1, a0); a1 = fmaf((float)v1[1], w1, a1);
            a2 = fmaf((float)v1[2], w1, a2); a3 = fmaf((float)v1[3], w1, a3);
            a0 = fmaf((float)v2[0], w2, a0); a1 = fmaf((float)v2[1], w2, a1);
            a2 = fmaf((float)v2[2], w2, a2); a3 = fmaf((float)v2[3], w2, a3);
            a0 = fmaf((float)v3[0], w3, a0); a1 = fmaf((float)v3[1], w3, a1);
            a2 = fmaf((float)v3[2], w3, a2); a3 = fmaf((float)v3[3], w3, a3);
        }
        for (; i < deg; ++i) {
            int s = csrc[e0 + i];
            float w = lap[4 * i];
            half4v v = *(const half4v*)(h16 + (size_t)s * HC + cb);
            a0 = fmaf((float)v[0], w, a0); a1 = fmaf((float)v[1], w, a1);
            a2 = fmaf((float)v[2], w, a2); a3 = fmaf((float)v[3], w, a3);
        }
    } else {
        const float* gap = (const float*)&galpha[e0] + comp;
        int i = 0;
        for (; i + 4 <= deg; i += 4) {
            int s0 = csrc[e0 + i], s1 = csrc[e0 + i + 1];
            int s2 = csrc[e0 + i + 2], s3 = csrc[e0 + i + 3];
            float w0 = gap[4 * i], w1 = gap[4 * (i + 1)];
            float w2 = gap[4 * (i + 2)], w3 = gap[4 * (i + 3)];
            half4v v0 = *(const half4v*)(h16 + (size_t)s0 * HC + cb);
            half4v v1 = *(const half4v*)(h16 + (size_t)s1 * HC + cb);
            half4v v2 = *(const half4v*)(h16 + (size_t)s2 * HC + cb);
            half4v v3 = *(const half4v*)(h16 + (size_t)s3 * HC + cb);
            a0 = fmaf((float)v0[0], w0, a0); a1 = fmaf((float)v0[1], w0, a1);
            a2 = fmaf((float)v0[2], w0, a2); a3 = fmaf((float)v0[3], w0, a3);
            a0 = fmaf((float)v1[0], w1, a0); a1 = fmaf((float)v1[1], w1, a1);
            a2 = fmaf((float)v1[2], w1, a2); a3 = fmaf((float)v1[3], w1, a3);
            a0 = fmaf((float)v2[0], w2, a0); a1 = fmaf((float)v2[1], w2, a1);
            a2 = fmaf((float)v2[2], w2, a2); a3 = fmaf((float)v2[3], w2, a3);
            a0 = fmaf((float)v3[0], w3, a0); a1 = fmaf((float)v3[1], w3, a1);
            a2 = fmaf((float)v3[2], w3, a2); a3 = fmaf((float)v3[3], w3, a3);
        }
        for (; i < deg; ++i) {
            int s = csrc[e0 + i];
            float w = gap[4 * i];
            half4v v = *(const half4v*)(h16 + (size_t)s * HC + cb);
            a0 = fmaf((float)v[0], w, a0); a1 = fmaf((float)v[1], w, a1);
            a2 = fmaf((float)v[2], w, a2); a3 = fmaf((float)v[3], w, a3);
        }
    }

    float4 bb = *(const float4*)&bias[cb];
    a0 += bb.x; a1 += bb.y; a2 += bb.z; a3 += bb.w;
    a0 = (a0 > 0.f) ? a0 : (__expf(a0) - 1.f);
    a1 = (a1 > 0.f) ? a1 : (__expf(a1) - 1.f);
    a2 = (a2 > 0.f) ? a2 : (__expf(a2) - 1.f);
    a3 = (a3 > 0.f) ? a3 : (__expf(a3) - 1.f);
    half4v o = {(_Float16)a0, (_Float16)a1, (_Float16)a2, (_Float16)a3};
    *(half4v*)(out16 + (size_t)node * HC + cb) = o;
}

// ---------------------------------------------------------------------------
// BatchNorm stats stage 1: per-block partials, no atomics.
// ---------------------------------------------------------------------------
__global__ __launch_bounds__(256) void bnstat_kernel(const _Float16* __restrict__ x,
                                                     double* __restrict__ partials,
                                                     int N) {
    __shared__ double lds[2][4][HC];            // 32 KiB
    int t = threadIdx.x;
    int lane = t & 63, wv = t >> 6;
    int c0 = lane * 8;
    const int stride = gridDim.x * 4;

    float s[8] = {}, q[8] = {};
    int r = blockIdx.x * 4 + wv;
    for (; r + stride < N; r += 2 * stride) {
        half8 v0 = *(const half8*)&x[(size_t)r * HC + c0];
        half8 v1 = *(const half8*)&x[(size_t)(r + stride) * HC + c0];
#pragma unroll
        for (int j = 0; j < 8; ++j) {
            float f0 = (float)v0[j], f1 = (float)v1[j];
            s[j] += f0 + f1;
            q[j] = fmaf(f0, f0, q[j]);
            q[j] = fmaf(f1, f1, q[j]);
        }
    }
    for (; r < N; r += stride) {
        half8 v0 = *(const half8*)&x[(size_t)r * HC + c0];
#pragma unroll
        for (int j = 0; j < 8; ++j) {
            float f0 = (float)v0[j];
            s[j] += f0;
            q[j] = fmaf(f0, f0, q[j]);
        }
    }
#pragma unroll
    for (int j = 0; j < 8; ++j) {
        lds[0][wv][c0 + j] = (double)s[j];
        lds[1][wv][c0 + j] = (double)q[j];
    }
    __syncthreads();
    if (wv == 0) {
        double* pb = partials + (size_t)blockIdx.x * 1024;
#pragma unroll
        for (int j = 0; j < 8; ++j) {
            int c = c0 + j;
            pb[c] = lds[0][0][c] + lds[0][1][c] + lds[0][2][c] + lds[0][3][c];
            pb[512 + c] = lds[1][0][c] + lds[1][1][c] + lds[1][2][c] + lds[1][3][c];
        }
    }
}

// ---------------------------------------------------------------------------
// bnadv: fused stage-2 reduce + BN-fold scalars.  One wave per channel;
// deterministic fixed-order lane-strided sum + shuffle tree for BOTH sum and
// sumsq, then lane 0 emits avec/dvec directly.
// ---------------------------------------------------------------------------
__global__ __launch_bounds__(256) void bnadv_kernel(const double* __restrict__ partials,
                                                    const float* __restrict__ g,
                                                    const float* __restrict__ bt,
                                                    float* __restrict__ avec,
                                                    float* __restrict__ dvec,
                                                    int nb, double invN) {
    int c = (blockIdx.x * 256 + threadIdx.x) >> 6;
    int lane = threadIdx.x & 63;
    if (c >= HC) return;
    double s = 0.0, qq = 0.0;
    for (int b = lane; b < nb; b += 64) {
        s += partials[(size_t)b * 1024 + c];
        qq += partials[(size_t)b * 1024 + 512 + c];
    }
#pragma unroll
    for (int off = 32; off; off >>= 1) {
        s += __shfl_xor(s, off);
        qq += __shfl_xor(qq, off);
    }
    if (lane == 0) {
        double mu = s * invN;
        double var = qq * invN - mu * mu;
        float a = g[c] * (float)rsqrt(var + (double)EPS_BN);
        avec[c] = a;
        dvec[c] = bt[c] - (float)mu * a;
    }
}

// ---------------------------------------------------------------------------
// Head: logits = x[N,64] @ w[64,10] + b; log_softmax.  One wave per row.
// ---------------------------------------------------------------------------
__global__ __launch_bounds__(256) void head_kernel(const float* __restrict__ x,
                                                   const float* __restrict__ w,
                                                   const float* __restrict__ b,
                                                   float* __restrict__ out, int N) {
    int wid = (blockIdx.x * 256 + threadIdx.x) >> 6;
    int lane = threadIdx.x & 63;
    if (wid >= N) return;
    float v = x[(size_t)wid * 64 + lane];
    float my = -INFINITY;
#pragma unroll
    for (int j = 0; j < 10; ++j) {
        float t = v * w[lane * 10 + j];
#pragma unroll
        for (int off = 32; off; off >>= 1) t += __shfl_xor(t, off);
        t += b[j];
        if (lane == j) my = t;
    }
    float mx = my;
#pragma unroll
    for (int off = 32; off; off >>= 1) mx = fmaxf(mx, __shfl_xor(mx, off));
    float p = (lane < 10) ? expf(my - mx) : 0.f;
    float sum = p;
#pragma unroll
    for (int off = 32; off; off >>= 1) sum += __shfl_xor(sum, off);
    if (lane < 10) out[(size_t)wid * 10 + lane] = my - mx - logf(sum);
}

// ---------------------------------------------------------------------------
extern "C" void kernel_launch(void* const* d_in, const int* in_sizes, int n_in,
                              void* d_out, int out_size, void* d_ws, size_t ws_size,
                              hipStream_t stream) {
    const float* x = (const float*)d_in[0];
    const int* ei = (const int*)d_in[1];        // [2, E] int32
    const int N = in_sizes[0] / 128;
    const int E = in_sizes[1] / 2;
    const int EN = E + N;
    const int NB_STAT = 256;

    // ---- workspace layout (8B-aligned sections) ----
    double* partials = (double*)d_ws;                            // 256*1024
    float* als   = (float*)(partials + (size_t)NB_STAT * 1024);  // N*4
    float* ald   = als + (size_t)N * NHEAD;                      // N*4
    float4* galpha = (float4*)(ald + (size_t)N * NHEAD);         // EN float4
    float* bvec  = (float*)(galpha + EN);                        // 512
    float* avec  = bvec + 512;                                   // 512
    float* dvec  = avec + 512;                                   // 512
    float* m1    = dvec + 512;                                   // N*128
    float* m2    = m1 + (size_t)N * 128;                         // N*64
    _Float16* xh   = (_Float16*)(m2 + (size_t)N * 64);           // N*128
    _Float16* h16  = xh + (size_t)N * 128;                       // N*512
    _Float16* out16 = h16 + (size_t)N * HC;                      // N*512
    _Float16* wpool = out16 + (size_t)N * HC;
    _Float16* wthi[4], * wtmhi;
    _Float16* p = wpool;
    wthi[0] = p; p += 512 * 128;
    for (int L = 1; L < 4; ++L) { wthi[L] = p; p += 512 * 512; }
    wtmhi = p; p += 128 * 512;
    int* rowptr = (int*)p;                                       // N+1
    int* wr = rowptr + (N + 1);                                  // N
    int* csrc = wr + N;                                          // EN

    // ---- CSR build (once) ----
    hipMemsetAsync(rowptr, 0, (N + 1) * sizeof(int), stream);
    hist_kernel<<<(EN + 255) / 256, 256, 0, stream>>>(ei + E, rowptr, E, N);
    scan_kernel<<<1, 1024, 0, stream>>>(rowptr, wr, N);
    scatter_kernel<<<(EN + 255) / 256, 256, 0, stream>>>(ei, ei + E, wr, csrc, E, N);

    // ---- layer-0 prep ----
    wsplit_kernel<<<dim3(512 / 32, 128 / 32), 256, 0, stream>>>(
        (const float*)d_in[3], nullptr, wthi[0], 128, 512);
    xcvt_kernel<<<1024, 256, 0, stream>>>(x, xh, N * 128);
    hipMemsetAsync(bvec, 0, 512 * sizeof(float), stream);

    const int nodeBlocks = (N * 64 + 255) / 256;
    const int gathBlocks = (N * 128 + 255) / 256;
    const double invN = 1.0 / (double)N;

    for (int L = 0; L < 4; ++L) {
        const float* as_ = (const float*)d_in[4 + 6 * L];
        const float* ad_ = (const float*)d_in[5 + 6 * L];
        const float* b_  = (const float*)d_in[6 + 6 * L];
        const float* g_  = (const float*)d_in[7 + 6 * L];
        const float* bt_ = (const float*)d_in[8 + 6 * L];
        const _Float16* Ain = (L == 0) ? xh : out16;
        const int curK = (L == 0) ? 128 : 512;

        mfma_gemm<0><<<dim3(HC / 128, (N + 127) / 128), 256, 0, stream>>>(
            Ain, wthi[L], bvec, h16, nullptr, N, curK, HC);
        al_kernel<<<nodeBlocks, 256, 0, stream>>>(h16, as_, ad_, als, ald, N);
        attgath_kernel<<<gathBlocks, 256, 0, stream>>>(h16, als, ald, rowptr, csrc,
                                                       galpha, b_, out16, N);
        bnstat_kernel<<<NB_STAT, 256, 0, stream>>>(out16, partials, N);
        bnadv_kernel<<<(HC * 64 + 255) / 256, 256, 0, stream>>>(
            partials, g_, bt_, avec, dvec, NB_STAT, invN);

        if (L < 3) {
            const float* Wn = (const float*)d_in[3 + 6 * (L + 1)];
            wsplit_kernel<<<dim3(512 / 32, 512 / 32), 256, 0, stream>>>(
                Wn, avec, wthi[L + 1], 512, 512);
            bvec_kernel<<<(512 * 64 + 255) / 256, 256, 0, stream>>>(
                Wn, dvec, nullptr, bvec, 512, 512);
        } else {
            const float* lw1 = (const float*)d_in[27];
            const float* lb1 = (const float*)d_in[28];
            wsplit_kernel<<<dim3(128 / 32, 512 / 32), 256, 0, stream>>>(
                lw1, avec, wtmhi, 512, 128);
            bvec_kernel<<<(128 * 64 + 255) / 256, 256, 0, stream>>>(
                lw1, dvec, lb1, bvec, 512, 128);
        }
    }

    // ---- MLP head ----
    const float* lw2 = (const float*)d_in[29];
    const float* lb2 = (const float*)d_in[30];
    const float* lw3 = (const float*)d_in[31];
    const float* lb3 = (const float*)d_in[32];

    mfma_gemm<1><<<dim3(1, (N + 127) / 128), 256, 0, stream>>>(
        out16, wtmhi, bvec, nullptr, m1, N, 512, 128);
    gemm_k<64, 64, 16, 4, 4, 1><<<dim3(1, (N + 63) / 64), 256, 0, stream>>>(
        m1, lw2, lb2, m2, N, 128, 64);
    head_kernel<<<nodeBlocks, 256, 0, stream>>>(m2, lw3, lb3, (float*)d_out, N);
}